// Round 9
// baseline (14051.569 us; speedup 1.0000x reference)
//
#include <hip/hip_runtime.h>
#include <stdint.h>

// ============================================================================
// ConViTCast: B=2 V=5 H=32 W=64 P=2 D=1024 NH=16 hd=64 DEPTH=2 L=512 BL=1024
// R8 this session: k_ode v12 — v10 mapping + 4x weight-blob replication.
// R8 evidence (v11): FETCH identical (5.68GB) across v9/v10/v11 placements ->
// placement is NOT the lever. v7 (no cross-block fences) had FETCH 0.91GB ->
// the group_barrier's agent-scope acquire fence invalidates the local L2
// (non-coherent per-XCD L2s) 3x/phase -> weights can NEVER be L2-retained in
// this structure. Volume (5.7GB) is fence-compulsory. Rate (~1TB/s) is
// same-line camping: 256 CUs re-read the SAME 4MB in lockstep; L3 serializes
// same-line requests. v11's XCC_ID claim also added a 27-47ms variance tail
// (claim-order placement) — reverted.
// v12: revert to v10's static (g,cg) map (passed 2x); replicate packed w1/w2
// blobs 4x (copies in ode-dead attno/t1/qkv-tail regions, rewritten by k_pack
// each depth); block pb reads copy (pb>>6)&3 -> 64 readers/copy.
// Predict: FETCH ~same, rate 3-4x, k_ode 6270 -> 1700-2500us.
// ============================================================================

#define NSTEPS 10
#define RESF 0.01f
#define EPSF 1e-5f

typedef unsigned short u16;
typedef unsigned int u32;
typedef __attribute__((ext_vector_type(8))) short bf16x8;
typedef __attribute__((ext_vector_type(4))) float f32x4;

// s_waitcnt vmcnt(N), ignore exp/lgkm (gfx9 encoding: vm[3:0]|[15:14], exp=7, lgkm=15)
#define VMCNT(N) __builtin_amdgcn_s_waitcnt(0x0F70 | ((N) & 0xF) | ((((N) >> 4) & 0x3) << 14))

__device__ __forceinline__ float b2f(u16 u) {
  return __uint_as_float(((uint32_t)u) << 16);
}
__device__ __forceinline__ u16 f2b(float f) {
  uint32_t x = __float_as_uint(f);
  uint32_t r = x + 0x7fffu + ((x >> 16) & 1u);  // round-to-nearest-even
  return (u16)(r >> 16);
}
__device__ __forceinline__ float red16(float v) {
  v += __shfl_xor(v, 1); v += __shfl_xor(v, 2);
  v += __shfl_xor(v, 4); v += __shfl_xor(v, 8);
  return v;
}

// Repack f32 weight [1024 cols][1024 k] -> bf16 MFMA-frag blob, 4 copies:
// blob[((ct*32+kk)*64+l)*8+j] = w[ct*16+(l&15)][kk*32+(l>>4)*8+j]
// Also zeroes the 64 group-barrier counters (first launch only).
__global__ __launch_bounds__(256) void k_pack(
    const float* __restrict__ in, u16* __restrict__ d0, u16* __restrict__ d1,
    u16* __restrict__ d2, u16* __restrict__ d3, u32* __restrict__ ctr) {
  int i = blockIdx.x * 256 + threadIdx.x;  // grid 4096 -> 1M elements
  int j = i & 7;
  int l = (i >> 3) & 63;
  int kk = (i >> 9) & 31;
  int ct = i >> 14;
  int col = ct * 16 + (l & 15);
  int k = kk * 32 + ((l >> 4) << 3) + j;
  u16 v = f2b(in[(size_t)col * 1024 + k]);
  d0[i] = v; d1[i] = v; d2[i] = v; d3[i] = v;
  if (ctr && blockIdx.x == 0 && threadIdx.x < 64) ctr[threadIdx.x] = 0;
}

// ---------------------------------------------------------------------------
// Extract patches[m*20 + v*4 + p] from x[b,v,h,w]; m=b*512+l, l=hh*32+ww
// ---------------------------------------------------------------------------
__global__ __launch_bounds__(256) void k_patches(
    const float* __restrict__ x, float* __restrict__ patches) {
  int i = blockIdx.x * 256 + threadIdx.x;  // grid 80*256 = 20480
  int m = i / 20, r = i % 20;
  int v = r >> 2, p = r & 3;
  int b = m >> 9, l = m & 511;
  int hh = l >> 5, ww = l & 31;
  int pr = p >> 1, pc = p & 1;
  patches[i] = x[((size_t)(b * 5 + v) * 32 + hh * 2 + pr) * 64 + ww * 2 + pc];
}

// qvec = var_query @ Wq^T + bq   (grid 64)
__global__ __launch_bounds__(256) void k_qvec(
    const float* __restrict__ vq, const float* __restrict__ w,
    const float* __restrict__ bias, float* __restrict__ qvec) {
  int dq = blockIdx.x * 16 + (threadIdx.x >> 4);
  int lane = threadIdx.x & 15;
  float p = 0.f;
  for (int j = 0; j < 64; j++) {
    int d = lane + 16 * j;
    p += vq[d] * w[(size_t)dq * 1024 + d];
  }
  p = red16(p);
  if (lane == 0) qvec[dq] = p + bias[dq];
}

// qb[h] = sum_e qvec[h*64+e]*bk[h*64+e]   (grid 1)
__global__ __launch_bounds__(256) void k_qb(
    const float* __restrict__ qvec, const float* __restrict__ bk,
    float* __restrict__ qb) {
  int h = threadIdx.x >> 4, lane = threadIdx.x & 15;
  float p = 0.f;
  for (int e = lane; e < 64; e += 16) p += qvec[h * 64 + e] * bk[h * 64 + e];
  p = red16(p);
  if (lane == 0) qb[h] = p;
}

// u[h][d] = sum_e qvec[h*64+e] * Wk[h*64+e][d]   (grid 64)
__global__ __launch_bounds__(256) void k_u(
    const float* __restrict__ qvec, const float* __restrict__ wk,
    float* __restrict__ u) {
  int d = blockIdx.x * 16 + (threadIdx.x & 15);
  int h = threadIdx.x >> 4;
  float acc = 0.f;
  for (int e = 0; e < 64; e++)
    acc += qvec[h * 64 + e] * wk[(size_t)(h * 64 + e) * 1024 + d];
  u[h * 1024 + d] = acc;
}

// PU[(v*16+h)*4+p] = 0.125*sum_d pw[v,d,p]*u[h,d]
// C0[v*16+h]       = 0.125*(sum_d (pb+ve)[v,d]*u[h,d] + qb[h])     (grid 80)
__global__ __launch_bounds__(256) void k_pu(
    const float* __restrict__ pw, const float* __restrict__ pb,
    const float* __restrict__ ve, const float* __restrict__ u,
    const float* __restrict__ qb, float* __restrict__ PU,
    float* __restrict__ C0) {
  int v = blockIdx.x / 16, h = blockIdx.x % 16;
  int t = threadIdx.x;
  float a0 = 0, a1 = 0, a2 = 0, a3 = 0, ac = 0;
  for (int d = t; d < 1024; d += 256) {
    float uu = u[h * 1024 + d];
    const float* p4 = pw + ((size_t)v * 1024 + d) * 4;
    a0 += p4[0] * uu; a1 += p4[1] * uu; a2 += p4[2] * uu; a3 += p4[3] * uu;
    ac += (pb[v * 1024 + d] + ve[v * 1024 + d]) * uu;
  }
  for (int off = 1; off < 64; off <<= 1) {
    a0 += __shfl_xor(a0, off); a1 += __shfl_xor(a1, off);
    a2 += __shfl_xor(a2, off); a3 += __shfl_xor(a3, off);
    ac += __shfl_xor(ac, off);
  }
  __shared__ float r[4][5];
  if ((t & 63) == 0) {
    int w = t >> 6;
    r[w][0] = a0; r[w][1] = a1; r[w][2] = a2; r[w][3] = a3; r[w][4] = ac;
  }
  __syncthreads();
  if (t == 0) {
    float s[5];
    for (int j = 0; j < 5; j++) s[j] = r[0][j] + r[1][j] + r[2][j] + r[3][j];
    float* pu = PU + (v * 16 + h) * 4;
    pu[0] = 0.125f * s[0]; pu[1] = 0.125f * s[1];
    pu[2] = 0.125f * s[2]; pu[3] = 0.125f * s[3];
    C0[v * 16 + h] = 0.125f * (s[4] + qb[h]);
  }
}

// PW[(v*1024+col)*4+p] = sum_d Wv[col,d]*pw[v,d,p]
// CV[v*1024+col]       = sum_d Wv[col,d]*(pb+ve)[v,d] + bv[col]    (grid 5120)
__global__ __launch_bounds__(256) void k_pw(
    const float* __restrict__ wv, const float* __restrict__ bv,
    const float* __restrict__ pw, const float* __restrict__ pb,
    const float* __restrict__ ve, float* __restrict__ PW,
    float* __restrict__ CV) {
  int v = blockIdx.x >> 10, col = blockIdx.x & 1023;
  int t = threadIdx.x;
  const float* wr = wv + (size_t)col * 1024;
  float4 w4 = *(const float4*)(wr + t * 4);
  float a0 = 0, a1 = 0, a2 = 0, a3 = 0, ac = 0;
#pragma unroll
  for (int j = 0; j < 4; j++) {
    int d = t * 4 + j;
    float wj = (j == 0) ? w4.x : (j == 1) ? w4.y : (j == 2) ? w4.z : w4.w;
    const float* p4 = pw + ((size_t)v * 1024 + d) * 4;
    a0 += wj * p4[0]; a1 += wj * p4[1]; a2 += wj * p4[2]; a3 += wj * p4[3];
    ac += wj * (pb[v * 1024 + d] + ve[v * 1024 + d]);
  }
  for (int off = 1; off < 64; off <<= 1) {
    a0 += __shfl_xor(a0, off); a1 += __shfl_xor(a1, off);
    a2 += __shfl_xor(a2, off); a3 += __shfl_xor(a3, off);
    ac += __shfl_xor(ac, off);
  }
  __shared__ float r[4][5];
  if ((t & 63) == 0) {
    int w = t >> 6;
    r[w][0] = a0; r[w][1] = a1; r[w][2] = a2; r[w][3] = a3; r[w][4] = ac;
  }
  __syncthreads();
  if (t == 0) {
    float s[5];
    for (int j = 0; j < 5; j++) s[j] = r[0][j] + r[1][j] + r[2][j] + r[3][j];
    float* o = PW + ((size_t)(v * 1024 + col)) * 4;
    o[0] = s[0]; o[1] = s[1]; o[2] = s[2]; o[3] = s[3];
    CV[v * 1024 + col] = s[4] + bv[col];
  }
}

// scores s[v][h] = patches[m,v]·PU[v,h] + C0[v,h]; softmax over v
// -> amat[m*80 + h*5 + v]                                          (grid 1024)
__global__ __launch_bounds__(256) void k_scoresm(
    const float* __restrict__ patches, const float* __restrict__ PU,
    const float* __restrict__ C0, float* __restrict__ amat) {
  __shared__ float pat[20];
  __shared__ float sa[16][8];
  int m = blockIdx.x, t = threadIdx.x;
  if (t < 20) pat[t] = patches[m * 20 + t];
  __syncthreads();
  if (t < 80) {
    int v = t / 16, h = t % 16;
    const float* pu = PU + (v * 16 + h) * 4;
    float s = C0[v * 16 + h] + pat[v * 4 + 0] * pu[0] + pat[v * 4 + 1] * pu[1]
            + pat[v * 4 + 2] * pu[2] + pat[v * 4 + 3] * pu[3];
    sa[h][v] = s;
  }
  __syncthreads();
  if (t < 16) {
    float mx = sa[t][0];
    for (int v = 1; v < 5; v++) mx = fmaxf(mx, sa[t][v]);
    float e[5], sum = 0.f;
    for (int v = 0; v < 5; v++) { e[v] = __expf(sa[t][v] - mx); sum += e[v]; }
    float inv = 1.f / sum;
    for (int v = 0; v < 5; v++) amat[m * 80 + t * 5 + v] = e[v] * inv;
  }
}

// agg[m,c] = sum_v amat[m,h(c),v] * (patches[m,v]·PW[v,c] + CV[v,c]) (grid 1024)
__global__ __launch_bounds__(256) void k_agg(
    const float* __restrict__ patches, const float* __restrict__ PW,
    const float* __restrict__ CV, const float* __restrict__ amat,
    float* __restrict__ agg) {
  __shared__ float pat[20];
  __shared__ float am[80];
  int m = blockIdx.x, t = threadIdx.x;
  if (t < 20) pat[t] = patches[m * 20 + t];
  if (t < 80) am[t] = amat[m * 80 + t];
  __syncthreads();
  int c0 = t * 4;
#pragma unroll
  for (int j = 0; j < 4; j++) {
    int c = c0 + j;
    int h = c >> 6;
    float acc = 0.f;
#pragma unroll
    for (int v = 0; v < 5; v++) {
      float4 w4 = *(const float4*)(PW + ((size_t)(v * 1024 + c)) * 4);
      float val = pat[v * 4 + 0] * w4.x + pat[v * 4 + 1] * w4.y
                + pat[v * 4 + 2] * w4.z + pat[v * 4 + 3] * w4.w
                + CV[v * 1024 + c];
      acc += am[h * 5 + v] * val;
    }
    agg[(size_t)m * 1024 + c] = acc;
  }
}

// ---------------------------------------------------------------------------
// Generic fp32 GEMM: C[M][N] = A[M][K] @ W[N][K]^T + bias, epilogues.
// EPI: 0 plain, 1 gelu(exact), 2 +resid, 3 +pos+lt
// ---------------------------------------------------------------------------
template <int EPI>
__global__ __launch_bounds__(256) void k_gemm(
    const float* __restrict__ A, const float* __restrict__ W,
    const float* __restrict__ bias, float* __restrict__ C,
    int M, int N, int K,
    const float* __restrict__ resid,
    const float* __restrict__ pos, const float* __restrict__ ltw,
    const float* __restrict__ ltb, const float* __restrict__ lead) {
  __shared__ float As[16][68];
  __shared__ float Ws[16][68];
  int m0 = blockIdx.y * 64, n0 = blockIdx.x * 64;
  int tid = threadIdx.x;
  int tx = tid & 15, ty = tid >> 4;
  int lr = tid & 63, lk = (tid >> 6) * 4;
  float acc[4][4] = {};
  for (int k0 = 0; k0 < K; k0 += 16) {
    float4 av = *(const float4*)(A + (size_t)(m0 + lr) * K + k0 + lk);
    float4 wv = {0.f, 0.f, 0.f, 0.f};
    if (n0 + lr < N) {
      wv = *(const float4*)(W + (size_t)(n0 + lr) * K + k0 + lk);
    }
    __syncthreads();
    As[lk + 0][lr] = av.x; As[lk + 1][lr] = av.y;
    As[lk + 2][lr] = av.z; As[lk + 3][lr] = av.w;
    Ws[lk + 0][lr] = wv.x; Ws[lk + 1][lr] = wv.y;
    Ws[lk + 2][lr] = wv.z; Ws[lk + 3][lr] = wv.w;
    __syncthreads();
#pragma unroll
    for (int kk = 0; kk < 16; kk++) {
      float4 a = *(const float4*)&As[kk][ty * 4];
      float4 b = *(const float4*)&Ws[kk][tx * 4];
      acc[0][0] += a.x * b.x; acc[0][1] += a.x * b.y; acc[0][2] += a.x * b.z; acc[0][3] += a.x * b.w;
      acc[1][0] += a.y * b.x; acc[1][1] += a.y * b.y; acc[1][2] += a.y * b.z; acc[1][3] += a.y * b.w;
      acc[2][0] += a.z * b.x; acc[2][1] += a.z * b.y; acc[2][2] += a.z * b.z; acc[2][3] += a.z * b.w;
      acc[3][0] += a.w * b.x; acc[3][1] += a.w * b.y; acc[3][2] += a.w * b.z; acc[3][3] += a.w * b.w;
    }
  }
#pragma unroll
  for (int ii = 0; ii < 4; ii++) {
    int m = m0 + ty * 4 + ii;
#pragma unroll
    for (int jj = 0; jj < 4; jj++) {
      int n = n0 + tx * 4 + jj;
      if (n >= N) continue;
      float v = acc[ii][jj] + bias[n];
      if (EPI == 1) v = 0.5f * v * (1.f + erff(v * 0.70710678118f));
      if (EPI == 2) v += resid[(size_t)m * N + n];
      if (EPI == 3) {
        int b = m >> 9, l = m & 511;
        v += pos[(size_t)l * 1024 + n] + ltw[n] * lead[b] + ltb[n];
      }
      C[(size_t)m * N + n] = v;
    }
  }
}

// ---------------------------------------------------------------------------
// LayerNorm over D=1024 (grid M). In-place safe.
// ---------------------------------------------------------------------------
__global__ __launch_bounds__(256) void k_ln(
    const float* __restrict__ src, const float* __restrict__ add,
    const float* __restrict__ g, const float* __restrict__ bb,
    float* __restrict__ dst) {
  __shared__ float red[8];
  int m = blockIdx.x, tid = threadIdx.x;
  float4 x = *(const float4*)(src + (size_t)m * 1024 + tid * 4);
  if (add) {
    float4 a2 = *(const float4*)(add + (size_t)m * 1024 + tid * 4);
    x.x += a2.x; x.y += a2.y; x.z += a2.z; x.w += a2.w;
  }
  float s1 = x.x + x.y + x.z + x.w;
  float s2 = x.x * x.x + x.y * x.y + x.z * x.z + x.w * x.w;
  for (int off = 1; off < 64; off <<= 1) {
    s1 += __shfl_xor(s1, off); s2 += __shfl_xor(s2, off);
  }
  if ((tid & 63) == 0) { red[(tid >> 6) * 2] = s1; red[(tid >> 6) * 2 + 1] = s2; }
  __syncthreads();
  s1 = red[0] + red[2] + red[4] + red[6];
  s2 = red[1] + red[3] + red[5] + red[7];
  float mean = s1 * (1.f / 1024.f);
  float var = s2 * (1.f / 1024.f) - mean * mean;
  float rstd = rsqrtf(var + EPSF);
  int c = tid * 4;
  float4 o;
  o.x = (x.x - mean) * rstd * g[c + 0] + bb[c + 0];
  o.y = (x.y - mean) * rstd * g[c + 1] + bb[c + 1];
  o.z = (x.z - mean) * rstd * g[c + 2] + bb[c + 2];
  o.w = (x.w - mean) * rstd * g[c + 3] + bb[c + 3];
  *(float4*)(dst + (size_t)m * 1024 + c) = o;
}

// ---------------------------------------------------------------------------
// Patch attention: per (b,h,ntile16). Two-pass softmax with S in LDS.
// ---------------------------------------------------------------------------
__global__ __launch_bounds__(256) void k_attn(
    const float* __restrict__ qkv, float* __restrict__ o) {
  __shared__ float Q[16][68];
  __shared__ float S[16][516];
  __shared__ float KV[32][68];
  int bid = blockIdx.x;
  int nt = bid & 31, h = (bid >> 5) & 15, b = bid >> 9;
  int tid = threadIdx.x;
  for (int i = tid; i < 16 * 64; i += 256) {
    int r = i >> 6, e = i & 63;
    Q[r][e] = qkv[(size_t)(b * 512 + nt * 16 + r) * 3072 + h * 64 + e];
  }
  __syncthreads();
  int r = tid >> 4, lane = tid & 15;
  for (int kt = 0; kt < 16; kt++) {
    for (int i = tid; i < 32 * 64; i += 256) {
      int rr = i >> 6, e = i & 63;
      KV[rr][e] = qkv[(size_t)(b * 512 + kt * 32 + rr) * 3072 + 1024 + h * 64 + e];
    }
    __syncthreads();
    for (int jj = lane; jj < 32; jj += 16) {
      float acc = 0.f;
#pragma unroll 8
      for (int e = 0; e < 64; e++) acc += Q[r][e] * KV[jj][e];
      S[r][kt * 32 + jj] = acc * 0.125f;
    }
    __syncthreads();
  }
  float mx = -1e30f;
  for (int j = lane; j < 512; j += 16) mx = fmaxf(mx, S[r][j]);
  for (int off = 1; off < 16; off <<= 1) mx = fmaxf(mx, __shfl_xor(mx, off));
  float sum = 0.f;
  for (int j = lane; j < 512; j += 16) {
    float e = __expf(S[r][j] - mx);
    S[r][j] = e; sum += e;
  }
  sum = red16(sum);
  float inv = 1.f / sum;
  int e0 = lane * 4;
  float4 accv = {0.f, 0.f, 0.f, 0.f};
  for (int kt = 0; kt < 16; kt++) {
    __syncthreads();
    for (int i = tid; i < 32 * 64; i += 256) {
      int rr = i >> 6, e = i & 63;
      KV[rr][e] = qkv[(size_t)(b * 512 + kt * 32 + rr) * 3072 + 2048 + h * 64 + e];
    }
    __syncthreads();
#pragma unroll 8
    for (int j = 0; j < 32; j++) {
      float p = S[r][kt * 32 + j] * inv;
      accv.x += p * KV[j][e0 + 0]; accv.y += p * KV[j][e0 + 1];
      accv.z += p * KV[j][e0 + 2]; accv.w += p * KV[j][e0 + 3];
    }
  }
  float* op = o + (size_t)(b * 512 + nt * 16 + r) * 1024 + h * 64 + e0;
  op[0] = accv.x; op[1] = accv.y; op[2] = accv.z; op[3] = accv.w;
}

// ---------------------------------------------------------------------------
// ODE persistent kernel v12 (v10 static map + 4x replicated weight blobs).
// Grid 256 = 64 token-groups (16 tokens) x 4 col-blocks (256 cols).
// Mapping: cg = (pb&7)>>1, g = ((pb>>3)<<1)|(pb&1) (v10, passed 2x).
// Block reads packed-weight copy rep=(pb>>6)&3 -> 64 readers/copy (breaks
// the 256-reader same-line L3 camping measured at ~1TB/s).
// Per phase: stage act(32KB)->bufA; GEMM1; write h slice; BAR; stage h->bufH;
// GEMM2; LN partials -> global; BAR; LN+RK4; write act slice; BAR.
// ---------------------------------------------------------------------------
__device__ __forceinline__ int swz(int m, int c) {
  int g = c >> 3;
  g = (g & ~7) | ((g ^ m) & 7);
  return m * 1024 + g * 8 + (c & 7);
}
__device__ __forceinline__ int swz8(int m, int k) {  // k multiple of 8
  int g = k >> 3;
  g = (g & ~7) | ((g ^ m) & 7);
  return m * 1024 + g * 8;
}

__device__ __forceinline__ void group_barrier(u32* ctr, u32 target, int tid) {
  __syncthreads();  // all block waves drained (vmcnt 0) before signal
  if (tid == 0) {
    __threadfence();  // release: writes visible device-scope (wb L2)
    __hip_atomic_fetch_add(ctr, 1u, __ATOMIC_RELEASE, __HIP_MEMORY_SCOPE_AGENT);
    while (__hip_atomic_load(ctr, __ATOMIC_ACQUIRE, __HIP_MEMORY_SCOPE_AGENT) < target) {
      __builtin_amdgcn_s_sleep(2);
    }
    __threadfence();  // acquire: invalidate stale L1/L2 lines
  }
  __syncthreads();
}

__global__ __launch_bounds__(1024, 4) void k_ode(
    const float* __restrict__ xs, float* __restrict__ out,
    const u16* __restrict__ w1p0, const u16* __restrict__ w1p1,
    const u16* __restrict__ w1p2, const u16* __restrict__ w1p3,
    const float* __restrict__ b1,
    const u16* __restrict__ w2p0, const u16* __restrict__ w2p1,
    const u16* __restrict__ w2p2, const u16* __restrict__ w2p3,
    const float* __restrict__ b2,
    const float* __restrict__ ng, const float* __restrict__ nb,
    const float* __restrict__ lead,
    u16* __restrict__ act_g, u16* __restrict__ h_g,
    float* __restrict__ pg, u32* __restrict__ ctr) {
  __shared__ __align__(16) u16 bufA[16 * 1024];
  __shared__ __align__(16) u16 bufH[16 * 1024];
  __shared__ float part_l[16][16][2];
  __shared__ float stats_l[16][2];
  int tid = threadIdx.x;
  // pb -> (g, cg): v10 static mapping (verified); replica by pb>>6
  int pb = blockIdx.x;
  int xl = pb & 7, sg = pb >> 3;
  int cg = xl >> 1;
  int g = (sg << 1) | (xl & 1);  // token group 0..63
  int rep = (pb >> 6) & 3;
  const u16* w1p = rep == 0 ? w1p0 : rep == 1 ? w1p1 : rep == 2 ? w1p2 : w1p3;
  const u16* w2p = rep == 0 ? w2p0 : rep == 1 ? w2p1 : rep == 2 ? w2p2 : w2p3;
  int m0 = g * 16;
  int wvid = tid >> 6, lane = tid & 63;
  int row16 = lane & 15, quad = lane >> 4;
  int n = cg * 256 + wvid * 16 + row16;  // this lane's output column
  int ct = cg * 16 + wvid;               // global col-tile 0..63
  u32* gc = ctr + g;
  // packed weight base for this wave's col-tile, this lane's frag slot
  const u16* wb1 = w1p + ((size_t)ct * 2048 + lane) * 8;  // ct*32kk*64l*8j
  const u16* wb2 = w2p + ((size_t)ct * 2048 + lane) * 8;

  float b1v = b1[n], b2v = b2[n], ngv = ng[n], nbv = nb[n];
  int idxb = (int)roundf(lead[m0 >> 9] * 100.0f);
  const float h6 = RESF / 6.0f;

  u16* actG = act_g + (size_t)g * 16384;
  u16* hG = h_g + (size_t)g * 16384;

  // ---- init state: y from xs; out init; act = bf16(y) (pre-swizzled) ----
  float yv[4], accr[4], nvv[4];
#pragma unroll
  for (int r = 0; r < 4; r++) {
    int ml = quad * 4 + r;
    float v = xs[(size_t)(m0 + ml) * 1024 + n];
    yv[r] = v; nvv[r] = v;
    out[(size_t)(m0 + ml) * 1024 + n] = v;
    actG[swz(ml, n)] = f2b(v);
  }
  u32 bar = 0;
  bar += 4; group_barrier(gc, bar, tid);

  for (int s = 0; s < NSTEPS; s++) {
    for (int ph = 0; ph < 4; ph++) {
      // ---- stage act -> bufA (per-lane global src, linear LDS dst) ----
      {
        const u16* src = actG + wvid * 1024 + lane * 8;
        u16* dst = bufA + wvid * 1024;
        __builtin_amdgcn_global_load_lds(
            (const __attribute__((address_space(1))) uint32_t*)src,
            (__attribute__((address_space(3))) uint32_t*)dst, 16, 0, 0);
        __builtin_amdgcn_global_load_lds(
            (const __attribute__((address_space(1))) uint32_t*)(src + 512),
            (__attribute__((address_space(3))) uint32_t*)(dst + 512), 16, 0, 0);
      }
      VMCNT(0);
      __syncthreads();
      // ---- GEMM1: h = relu(act @ w1^T + b1), wave's 16 cols ----
      f32x4 acc = {0.f, 0.f, 0.f, 0.f};
#pragma unroll
      for (int kk = 0; kk < 32; kk++) {
        bf16x8 wf = *(const bf16x8*)(wb1 + kk * 512);
        bf16x8 aF = *(const bf16x8*)(bufA + swz8(row16, kk * 32 + quad * 8));
        acc = __builtin_amdgcn_mfma_f32_16x16x32_bf16(aF, wf, acc, 0, 0, 0);
      }
#pragma unroll
      for (int r = 0; r < 4; r++) {
        int ml = quad * 4 + r;
        hG[swz(ml, n)] = f2b(fmaxf(acc[r] + b1v, 0.f));
      }
      bar += 4; group_barrier(gc, bar, tid);
      // ---- stage h -> bufH ----
      {
        const u16* src = hG + wvid * 1024 + lane * 8;
        u16* dst = bufH + wvid * 1024;
        __builtin_amdgcn_global_load_lds(
            (const __attribute__((address_space(1))) uint32_t*)src,
            (__attribute__((address_space(3))) uint32_t*)dst, 16, 0, 0);
        __builtin_amdgcn_global_load_lds(
            (const __attribute__((address_space(1))) uint32_t*)(src + 512),
            (__attribute__((address_space(3))) uint32_t*)(dst + 512), 16, 0, 0);
      }
      VMCNT(0);
      __syncthreads();
      // ---- GEMM2: z = h @ w2^T + b2 + resid ----
      f32x4 acc2 = {0.f, 0.f, 0.f, 0.f};
#pragma unroll
      for (int kk = 0; kk < 32; kk++) {
        bf16x8 wf = *(const bf16x8*)(wb2 + kk * 512);
        bf16x8 hF = *(const bf16x8*)(bufH + swz8(row16, kk * 32 + quad * 8));
        acc2 = __builtin_amdgcn_mfma_f32_16x16x32_bf16(hF, wf, acc2, 0, 0, 0);
      }
      float z[4];
#pragma unroll
      for (int r = 0; r < 4; r++) {
        z[r] = acc2[r] + b2v + nvv[r];
        float a = z[r], bsq = z[r] * z[r];
        a += __shfl_xor(a, 1); a += __shfl_xor(a, 2);
        a += __shfl_xor(a, 4); a += __shfl_xor(a, 8);
        bsq += __shfl_xor(bsq, 1); bsq += __shfl_xor(bsq, 2);
        bsq += __shfl_xor(bsq, 4); bsq += __shfl_xor(bsq, 8);
        if (row16 == 0) {
          part_l[wvid][quad * 4 + r][0] = a;
          part_l[wvid][quad * 4 + r][1] = bsq;
        }
      }
      __syncthreads();
      if (tid < 32) {
        int row = tid & 15, c = tid >> 4;
        float tot = 0.f;
#pragma unroll
        for (int w = 0; w < 16; w++) tot += part_l[w][row][c];
        pg[(((size_t)g * 4 + cg) * 16 + row) * 2 + c] = tot;
      }
      bar += 4; group_barrier(gc, bar, tid);
      if (tid < 32) {
        int row = tid & 15, c = tid >> 4;
        float tot = 0.f;
#pragma unroll
        for (int j = 0; j < 4; j++)
          tot += pg[(((size_t)g * 4 + j) * 16 + row) * 2 + c];
        stats_l[row][c] = tot;
      }
      __syncthreads();
      // ---- LN + RK4 state update; write act slice for next phase ----
      float cf = (ph < 2) ? 0.5f * RESF : RESF;
#pragma unroll
      for (int r = 0; r < 4; r++) {
        int ml = quad * 4 + r;
        float mean = stats_l[ml][0] * (1.f / 1024.f);
        float var = stats_l[ml][1] * (1.f / 1024.f) - mean * mean;
        float rstd = rsqrtf(var + EPSF);
        float k = (z[r] - mean) * rstd * ngv + nbv;
        if (ph == 0)      { accr[r] = k;        nvv[r] = yv[r] + cf * k; }
        else if (ph < 3)  { accr[r] += 2.f * k; nvv[r] = yv[r] + cf * k; }
        else              { yv[r] += h6 * (accr[r] + k); nvv[r] = yv[r]; }
        actG[swz(ml, n)] = f2b(nvv[r]);
      }
      if (ph == 3 && (s + 1) == idxb) {
#pragma unroll
        for (int r = 0; r < 4; r++)
          out[(size_t)(m0 + quad * 4 + r) * 1024 + n] = yv[r];
      }
      bar += 4; group_barrier(gc, bar, tid);
    }
  }
}

// ---------------------------------------------------------------------------
// Unpatchify: y3[m][p*10+q*5+c] -> out[b][c][hh*2+p][ww*2+q], FLOAT32
// ---------------------------------------------------------------------------
__global__ __launch_bounds__(256) void k_unpatch(
    const float* __restrict__ y3, float* __restrict__ outp) {
  int o = blockIdx.x * 256 + threadIdx.x;
  if (o >= 20480) return;
  int b = o / 10240;
  int c = (o / 2048) % 5;
  int hrow = (o / 64) % 32;
  int wcol = o % 64;
  int hh = hrow >> 1, p = hrow & 1, ww = wcol >> 1, q = wcol & 1;
  int m2 = b * 512 + hh * 32 + ww;
  int colj = p * 10 + q * 5 + c;
  outp[o] = y3[(size_t)m2 * 20 + colj];
}

// ===========================================================================
extern "C" void kernel_launch(void* const* d_in, const int* in_sizes, int n_in,
                              void* d_out, int out_size, void* d_ws, size_t ws_size,
                              hipStream_t stream) {
  const float* x         = (const float*)d_in[0];
  const float* lead      = (const float*)d_in[1];
  const float* patch_w   = (const float*)d_in[2];
  const float* patch_b   = (const float*)d_in[3];
  const float* var_embed = (const float*)d_in[4];
  const float* var_query = (const float*)d_in[5];
  const float* agg_in_w  = (const float*)d_in[6];
  const float* agg_in_b  = (const float*)d_in[7];
  const float* agg_out_w = (const float*)d_in[8];
  const float* agg_out_b = (const float*)d_in[9];
  const float* pos_embed = (const float*)d_in[10];
  const float* lt_w      = (const float*)d_in[11];
  const float* lt_b      = (const float*)d_in[12];
  const float* blk_qkv_w = (const float*)d_in[13];
  const float* blk_qkv_b = (const float*)d_in[14];
  const float* blk_out_w = (const float*)d_in[15];
  const float* blk_out_b = (const float*)d_in[16];
  const float* blk_n1_g  = (const float*)d_in[17];
  const float* blk_n1_b  = (const float*)d_in[18];
  const float* blk_n2_g  = (const float*)d_in[19];
  const float* blk_n2_b  = (const float*)d_in[20];
  const float* ode_w1    = (const float*)d_in[21];
  const float* ode_b1    = (const float*)d_in[22];
  const float* ode_w2    = (const float*)d_in[23];
  const float* ode_b2    = (const float*)d_in[24];
  const float* ode_ng    = (const float*)d_in[25];
  const float* ode_nb    = (const float*)d_in[26];
  const float* norm_g    = (const float*)d_in[27];
  const float* norm_b    = (const float*)d_in[28];
  const float* h1_w      = (const float*)d_in[29];
  const float* h1_b      = (const float*)d_in[30];
  const float* h2_w      = (const float*)d_in[31];
  const float* h2_b      = (const float*)d_in[32];
  const float* hf_w      = (const float*)d_in[33];
  const float* hf_b      = (const float*)d_in[34];
  (void)in_sizes; (void)n_in; (void)out_size; (void)ws_size;

  float* ws = (float*)d_ws;
  // k_ode exchange buffers live in the (dead-during-ode) qkv region at ws+0:
  u16*   act_g = (u16*)(ws + 0);        // 2MB  (524288 floats)
  u16*   h_g   = (u16*)(ws + 524288);   // 2MB
  float* pgb   = ws + 1048576;          // 8192 floats
  u32*   ctrp  = (u32*)(ws + 1056768);  // 64 barrier ctrs
  // replicated packed weight blobs (each 2MB = 524288 floats):
  //  copy0: w16a/w16b (canonical, 28-32MB); copy1: attno region (12-16MB);
  //  copy2: t1 region (16-20MB); copy3: qkv-tail (5-9MB). All ode-dead,
  //  rewritten by k_pack AFTER their last non-ode use each depth iteration.
  u16*   w1r3  = (u16*)(ws + 1310720);  // 5-7MB   (qkv tail; > ctr end 4.23MB)
  u16*   w2r3  = (u16*)(ws + 1835008);  // 7-9MB
  u16*   w1r1  = (u16*)(ws + 3145728);  // 12-14MB (attno)
  u16*   w2r1  = (u16*)(ws + 3670016);  // 14-16MB
  u16*   w1r2  = (u16*)(ws + 4194304);  // 16-18MB (t1)
  u16*   w2r2  = (u16*)(ws + 4718592);  // 18-20MB
  float* patches = ws + 0;         // 20480 (stage-1 only; dead before ode)
  float* qvec    = ws + 20480;     // 1024
  float* qb      = ws + 21504;     // 256 (16 used)
  float* u       = ws + 21760;     // 16384
  float* PU      = ws + 38144;     // 320
  float* C0      = ws + 38464;     // 80 (pad to 40960)
  float* amat    = ws + 40960;     // 81920
  float* PW      = ws + 122880;    // 20480
  float* CV      = ws + 143360;    // 5120  (end 148480 < 1048576)
  float* agg     = ws + 3145728;   // 1048576 (attno slot; dead by then)
  float* qkv   = ws + 0;           // 3145728
  float* attno = ws + 3145728;     // 1048576
  float* t1    = ws + 4194304;     // 1048576
  float* odeo  = ws + 5242880;     // 1048576
  float* xs    = ws + 6291456;     // 1048576
  u16*   w16a  = (u16*)(ws + 7340032);  // canonical packed w1 (copy0)
  u16*   w16b  = (u16*)(ws + 7864320);  // canonical packed w2 (copy0)
  float* y1 = ws + 0;
  float* y2 = ws + 1048576;
  float* y3 = ws + 2097152;        // 20480

  // ---- stage 1 ----
  k_patches<<<dim3(80), dim3(256), 0, stream>>>(x, patches);
  k_qvec<<<dim3(64), dim3(256), 0, stream>>>(var_query, agg_in_w, agg_in_b, qvec);
  k_qb<<<dim3(1), dim3(256), 0, stream>>>(qvec, agg_in_b + 1024, qb);
  k_u<<<dim3(64), dim3(256), 0, stream>>>(qvec, agg_in_w + (size_t)1024 * 1024, u);
  k_pu<<<dim3(80), dim3(256), 0, stream>>>(patch_w, patch_b, var_embed, u, qb, PU, C0);
  k_pw<<<dim3(5120), dim3(256), 0, stream>>>(
      agg_in_w + (size_t)2048 * 1024, agg_in_b + 2048, patch_w, patch_b,
      var_embed, PW, CV);
  k_scoresm<<<dim3(1024), dim3(256), 0, stream>>>(patches, PU, C0, amat);
  k_agg<<<dim3(1024), dim3(256), 0, stream>>>(patches, PW, CV, amat, agg);
  k_gemm<3><<<dim3(16, 16), dim3(256), 0, stream>>>(
      agg, agg_out_w, agg_out_b, xs, 1024, 1024, 1024,
      nullptr, pos_embed, lt_w, lt_b, lead);

  // ---- transformer blocks ----
  for (int i = 0; i < 2; i++) {
    k_gemm<0><<<dim3(48, 16), dim3(256), 0, stream>>>(
        xs, blk_qkv_w + (size_t)i * 3072 * 1024, blk_qkv_b + i * 3072, qkv,
        1024, 3072, 1024, nullptr, nullptr, nullptr, nullptr, nullptr);
    k_attn<<<dim3(1024), dim3(256), 0, stream>>>(qkv, attno);
    k_gemm<2><<<dim3(16, 16), dim3(256), 0, stream>>>(
        attno, blk_out_w + (size_t)i * 1048576, blk_out_b + i * 1024, t1,
        1024, 1024, 1024, xs, nullptr, nullptr, nullptr, nullptr);
    k_ln<<<dim3(1024), dim3(256), 0, stream>>>(
        t1, (const float*)nullptr, blk_n1_g + i * 1024, blk_n1_b + i * 1024, xs);
    k_pack<<<dim3(4096), dim3(256), 0, stream>>>(
        ode_w1 + (size_t)i * 1048576, w16a, w1r1, w1r2, w1r3, ctrp);  // + ctr zero
    k_pack<<<dim3(4096), dim3(256), 0, stream>>>(
        ode_w2 + (size_t)i * 1048576, w16b, w2r1, w2r2, w2r3, (u32*)nullptr);
    k_ode<<<dim3(256), dim3(1024), 0, stream>>>(
        xs, odeo, w16a, w1r1, w1r2, w1r3, ode_b1 + i * 1024,
        w16b, w2r1, w2r2, w2r3, ode_b2 + i * 1024,
        ode_ng + i * 1024, ode_nb + i * 1024, lead,
        act_g, h_g, pgb, ctrp);
    k_ln<<<dim3(1024), dim3(256), 0, stream>>>(
        xs, odeo, blk_n2_g + i * 1024, blk_n2_b + i * 1024, xs);
  }

  // ---- head ----
  k_ln<<<dim3(1024), dim3(256), 0, stream>>>(
      xs, (const float*)nullptr, norm_g, norm_b, xs);
  k_gemm<1><<<dim3(16, 16), dim3(256), 0, stream>>>(
      xs, h1_w, h1_b, y1, 1024, 1024, 1024, nullptr, nullptr, nullptr, nullptr, nullptr);
  k_gemm<1><<<dim3(16, 16), dim3(256), 0, stream>>>(
      y1, h2_w, h2_b, y2, 1024, 1024, 1024, nullptr, nullptr, nullptr, nullptr, nullptr);
  k_gemm<0><<<dim3(1, 16), dim3(256), 0, stream>>>(
      y2, hf_w, hf_b, y3, 1024, 20, 1024, nullptr, nullptr, nullptr, nullptr, nullptr);
  k_unpatch<<<dim3(80), dim3(256), 0, stream>>>(y3, (float*)d_out);
}

// Round 10
// 3125.429 us; speedup vs baseline: 4.4959x; 4.4959x over previous
//
#include <hip/hip_runtime.h>
#include <stdint.h>

// ============================================================================
// ConViTCast: B=2 V=5 H=32 W=64 P=2 D=1024 NH=16 hd=64 DEPTH=2 L=512 BL=1024
// R9 this session: k_ode v13 — fence-free: kernel-per-phase pipeline.
// Evidence chain: v9/v10/v11/v12 all FETCH 5.7GB @ ~1TB/s (placement change,
// HW-ID claim, 4x replication ALL no-ops) vs v7 FETCH 0.91GB (no cross-block
// fences). Conclusion: the group_barrier's agent acquire fence invalidates
// the per-XCD L2 3x/phase -> weights can never be cache-resident in ANY
// fenced persistent structure. Fix: drop the persistent kernel entirely.
// v13: host loop, 3 kernels/phase (stream order = sync, zero fences):
//  k_og<1>: GEMM1 (v9's verified MFMA/staging/swz) -> relu -> h image
//  k_og<2>: GEMM2 -> raw f32 zraw
//  k_rk4:  z=zraw+b2+nv(f32); row-LN; RK4 on f32 y/accr/nv; next act image
// Arithmetic path identical to the passed v9-v12 kernels (f32 resid kept).
// Predict: k_og ~5-15us x160, k_rk4 ~3-5us x80, FETCH/launch <=10MB,
// total 14.05 -> 3.5-5ms.
// ============================================================================

#define NSTEPS 10
#define RESF 0.01f
#define EPSF 1e-5f

typedef unsigned short u16;
typedef unsigned int u32;
typedef __attribute__((ext_vector_type(8))) short bf16x8;
typedef __attribute__((ext_vector_type(4))) float f32x4;

// s_waitcnt vmcnt(N), ignore exp/lgkm (gfx9 encoding: vm[3:0]|[15:14], exp=7, lgkm=15)
#define VMCNT(N) __builtin_amdgcn_s_waitcnt(0x0F70 | ((N) & 0xF) | ((((N) >> 4) & 0x3) << 14))

__device__ __forceinline__ float b2f(u16 u) {
  return __uint_as_float(((uint32_t)u) << 16);
}
__device__ __forceinline__ u16 f2b(float f) {
  uint32_t x = __float_as_uint(f);
  uint32_t r = x + 0x7fffu + ((x >> 16) & 1u);  // round-to-nearest-even
  return (u16)(r >> 16);
}
__device__ __forceinline__ float red16(float v) {
  v += __shfl_xor(v, 1); v += __shfl_xor(v, 2);
  v += __shfl_xor(v, 4); v += __shfl_xor(v, 8);
  return v;
}

// Repack f32 weight [1024 cols][1024 k] -> bf16 MFMA-frag blob:
// blob[((ct*32+kk)*64+l)*8+j] = w[ct*16+(l&15)][kk*32+(l>>4)*8+j]
__global__ __launch_bounds__(256) void k_pack(
    const float* __restrict__ in, u16* __restrict__ out16) {
  int i = blockIdx.x * 256 + threadIdx.x;  // grid 4096 -> 1M elements
  int j = i & 7;
  int l = (i >> 3) & 63;
  int kk = (i >> 9) & 31;
  int ct = i >> 14;
  int col = ct * 16 + (l & 15);
  int k = kk * 32 + ((l >> 4) << 3) + j;
  out16[i] = f2b(in[(size_t)col * 1024 + k]);
}

// ---------------------------------------------------------------------------
// Extract patches[m*20 + v*4 + p] from x[b,v,h,w]; m=b*512+l, l=hh*32+ww
// ---------------------------------------------------------------------------
__global__ __launch_bounds__(256) void k_patches(
    const float* __restrict__ x, float* __restrict__ patches) {
  int i = blockIdx.x * 256 + threadIdx.x;  // grid 80*256 = 20480
  int m = i / 20, r = i % 20;
  int v = r >> 2, p = r & 3;
  int b = m >> 9, l = m & 511;
  int hh = l >> 5, ww = l & 31;
  int pr = p >> 1, pc = p & 1;
  patches[i] = x[((size_t)(b * 5 + v) * 32 + hh * 2 + pr) * 64 + ww * 2 + pc];
}

// qvec = var_query @ Wq^T + bq   (grid 64)
__global__ __launch_bounds__(256) void k_qvec(
    const float* __restrict__ vq, const float* __restrict__ w,
    const float* __restrict__ bias, float* __restrict__ qvec) {
  int dq = blockIdx.x * 16 + (threadIdx.x >> 4);
  int lane = threadIdx.x & 15;
  float p = 0.f;
  for (int j = 0; j < 64; j++) {
    int d = lane + 16 * j;
    p += vq[d] * w[(size_t)dq * 1024 + d];
  }
  p = red16(p);
  if (lane == 0) qvec[dq] = p + bias[dq];
}

// qb[h] = sum_e qvec[h*64+e]*bk[h*64+e]   (grid 1)
__global__ __launch_bounds__(256) void k_qb(
    const float* __restrict__ qvec, const float* __restrict__ bk,
    float* __restrict__ qb) {
  int h = threadIdx.x >> 4, lane = threadIdx.x & 15;
  float p = 0.f;
  for (int e = lane; e < 64; e += 16) p += qvec[h * 64 + e] * bk[h * 64 + e];
  p = red16(p);
  if (lane == 0) qb[h] = p;
}

// u[h][d] = sum_e qvec[h*64+e] * Wk[h*64+e][d]   (grid 64)
__global__ __launch_bounds__(256) void k_u(
    const float* __restrict__ qvec, const float* __restrict__ wk,
    float* __restrict__ u) {
  int d = blockIdx.x * 16 + (threadIdx.x & 15);
  int h = threadIdx.x >> 4;
  float acc = 0.f;
  for (int e = 0; e < 64; e++)
    acc += qvec[h * 64 + e] * wk[(size_t)(h * 64 + e) * 1024 + d];
  u[h * 1024 + d] = acc;
}

// PU[(v*16+h)*4+p] = 0.125*sum_d pw[v,d,p]*u[h,d]
// C0[v*16+h]       = 0.125*(sum_d (pb+ve)[v,d]*u[h,d] + qb[h])     (grid 80)
__global__ __launch_bounds__(256) void k_pu(
    const float* __restrict__ pw, const float* __restrict__ pb,
    const float* __restrict__ ve, const float* __restrict__ u,
    const float* __restrict__ qb, float* __restrict__ PU,
    float* __restrict__ C0) {
  int v = blockIdx.x / 16, h = blockIdx.x % 16;
  int t = threadIdx.x;
  float a0 = 0, a1 = 0, a2 = 0, a3 = 0, ac = 0;
  for (int d = t; d < 1024; d += 256) {
    float uu = u[h * 1024 + d];
    const float* p4 = pw + ((size_t)v * 1024 + d) * 4;
    a0 += p4[0] * uu; a1 += p4[1] * uu; a2 += p4[2] * uu; a3 += p4[3] * uu;
    ac += (pb[v * 1024 + d] + ve[v * 1024 + d]) * uu;
  }
  for (int off = 1; off < 64; off <<= 1) {
    a0 += __shfl_xor(a0, off); a1 += __shfl_xor(a1, off);
    a2 += __shfl_xor(a2, off); a3 += __shfl_xor(a3, off);
    ac += __shfl_xor(ac, off);
  }
  __shared__ float r[4][5];
  if ((t & 63) == 0) {
    int w = t >> 6;
    r[w][0] = a0; r[w][1] = a1; r[w][2] = a2; r[w][3] = a3; r[w][4] = ac;
  }
  __syncthreads();
  if (t == 0) {
    float s[5];
    for (int j = 0; j < 5; j++) s[j] = r[0][j] + r[1][j] + r[2][j] + r[3][j];
    float* pu = PU + (v * 16 + h) * 4;
    pu[0] = 0.125f * s[0]; pu[1] = 0.125f * s[1];
    pu[2] = 0.125f * s[2]; pu[3] = 0.125f * s[3];
    C0[v * 16 + h] = 0.125f * (s[4] + qb[h]);
  }
}

// PW[(v*1024+col)*4+p] = sum_d Wv[col,d]*pw[v,d,p]
// CV[v*1024+col]       = sum_d Wv[col,d]*(pb+ve)[v,d] + bv[col]    (grid 5120)
__global__ __launch_bounds__(256) void k_pw(
    const float* __restrict__ wv, const float* __restrict__ bv,
    const float* __restrict__ pw, const float* __restrict__ pb,
    const float* __restrict__ ve, float* __restrict__ PW,
    float* __restrict__ CV) {
  int v = blockIdx.x >> 10, col = blockIdx.x & 1023;
  int t = threadIdx.x;
  const float* wr = wv + (size_t)col * 1024;
  float4 w4 = *(const float4*)(wr + t * 4);
  float a0 = 0, a1 = 0, a2 = 0, a3 = 0, ac = 0;
#pragma unroll
  for (int j = 0; j < 4; j++) {
    int d = t * 4 + j;
    float wj = (j == 0) ? w4.x : (j == 1) ? w4.y : (j == 2) ? w4.z : w4.w;
    const float* p4 = pw + ((size_t)v * 1024 + d) * 4;
    a0 += wj * p4[0]; a1 += wj * p4[1]; a2 += wj * p4[2]; a3 += wj * p4[3];
    ac += wj * (pb[v * 1024 + d] + ve[v * 1024 + d]);
  }
  for (int off = 1; off < 64; off <<= 1) {
    a0 += __shfl_xor(a0, off); a1 += __shfl_xor(a1, off);
    a2 += __shfl_xor(a2, off); a3 += __shfl_xor(a3, off);
    ac += __shfl_xor(ac, off);
  }
  __shared__ float r[4][5];
  if ((t & 63) == 0) {
    int w = t >> 6;
    r[w][0] = a0; r[w][1] = a1; r[w][2] = a2; r[w][3] = a3; r[w][4] = ac;
  }
  __syncthreads();
  if (t == 0) {
    float s[5];
    for (int j = 0; j < 5; j++) s[j] = r[0][j] + r[1][j] + r[2][j] + r[3][j];
    float* o = PW + ((size_t)(v * 1024 + col)) * 4;
    o[0] = s[0]; o[1] = s[1]; o[2] = s[2]; o[3] = s[3];
    CV[v * 1024 + col] = s[4] + bv[col];
  }
}

// scores s[v][h] = patches[m,v]·PU[v,h] + C0[v,h]; softmax over v
// -> amat[m*80 + h*5 + v]                                          (grid 1024)
__global__ __launch_bounds__(256) void k_scoresm(
    const float* __restrict__ patches, const float* __restrict__ PU,
    const float* __restrict__ C0, float* __restrict__ amat) {
  __shared__ float pat[20];
  __shared__ float sa[16][8];
  int m = blockIdx.x, t = threadIdx.x;
  if (t < 20) pat[t] = patches[m * 20 + t];
  __syncthreads();
  if (t < 80) {
    int v = t / 16, h = t % 16;
    const float* pu = PU + (v * 16 + h) * 4;
    float s = C0[v * 16 + h] + pat[v * 4 + 0] * pu[0] + pat[v * 4 + 1] * pu[1]
            + pat[v * 4 + 2] * pu[2] + pat[v * 4 + 3] * pu[3];
    sa[h][v] = s;
  }
  __syncthreads();
  if (t < 16) {
    float mx = sa[t][0];
    for (int v = 1; v < 5; v++) mx = fmaxf(mx, sa[t][v]);
    float e[5], sum = 0.f;
    for (int v = 0; v < 5; v++) { e[v] = __expf(sa[t][v] - mx); sum += e[v]; }
    float inv = 1.f / sum;
    for (int v = 0; v < 5; v++) amat[m * 80 + t * 5 + v] = e[v] * inv;
  }
}

// agg[m,c] = sum_v amat[m,h(c),v] * (patches[m,v]·PW[v,c] + CV[v,c]) (grid 1024)
__global__ __launch_bounds__(256) void k_agg(
    const float* __restrict__ patches, const float* __restrict__ PW,
    const float* __restrict__ CV, const float* __restrict__ amat,
    float* __restrict__ agg) {
  __shared__ float pat[20];
  __shared__ float am[80];
  int m = blockIdx.x, t = threadIdx.x;
  if (t < 20) pat[t] = patches[m * 20 + t];
  if (t < 80) am[t] = amat[m * 80 + t];
  __syncthreads();
  int c0 = t * 4;
#pragma unroll
  for (int j = 0; j < 4; j++) {
    int c = c0 + j;
    int h = c >> 6;
    float acc = 0.f;
#pragma unroll
    for (int v = 0; v < 5; v++) {
      float4 w4 = *(const float4*)(PW + ((size_t)(v * 1024 + c)) * 4);
      float val = pat[v * 4 + 0] * w4.x + pat[v * 4 + 1] * w4.y
                + pat[v * 4 + 2] * w4.z + pat[v * 4 + 3] * w4.w
                + CV[v * 1024 + c];
      acc += am[h * 5 + v] * val;
    }
    agg[(size_t)m * 1024 + c] = acc;
  }
}

// ---------------------------------------------------------------------------
// Generic fp32 GEMM: C[M][N] = A[M][K] @ W[N][K]^T + bias, epilogues.
// EPI: 0 plain, 1 gelu(exact), 2 +resid, 3 +pos+lt
// ---------------------------------------------------------------------------
template <int EPI>
__global__ __launch_bounds__(256) void k_gemm(
    const float* __restrict__ A, const float* __restrict__ W,
    const float* __restrict__ bias, float* __restrict__ C,
    int M, int N, int K,
    const float* __restrict__ resid,
    const float* __restrict__ pos, const float* __restrict__ ltw,
    const float* __restrict__ ltb, const float* __restrict__ lead) {
  __shared__ float As[16][68];
  __shared__ float Ws[16][68];
  int m0 = blockIdx.y * 64, n0 = blockIdx.x * 64;
  int tid = threadIdx.x;
  int tx = tid & 15, ty = tid >> 4;
  int lr = tid & 63, lk = (tid >> 6) * 4;
  float acc[4][4] = {};
  for (int k0 = 0; k0 < K; k0 += 16) {
    float4 av = *(const float4*)(A + (size_t)(m0 + lr) * K + k0 + lk);
    float4 wv = {0.f, 0.f, 0.f, 0.f};
    if (n0 + lr < N) {
      wv = *(const float4*)(W + (size_t)(n0 + lr) * K + k0 + lk);
    }
    __syncthreads();
    As[lk + 0][lr] = av.x; As[lk + 1][lr] = av.y;
    As[lk + 2][lr] = av.z; As[lk + 3][lr] = av.w;
    Ws[lk + 0][lr] = wv.x; Ws[lk + 1][lr] = wv.y;
    Ws[lk + 2][lr] = wv.z; Ws[lk + 3][lr] = wv.w;
    __syncthreads();
#pragma unroll
    for (int kk = 0; kk < 16; kk++) {
      float4 a = *(const float4*)&As[kk][ty * 4];
      float4 b = *(const float4*)&Ws[kk][tx * 4];
      acc[0][0] += a.x * b.x; acc[0][1] += a.x * b.y; acc[0][2] += a.x * b.z; acc[0][3] += a.x * b.w;
      acc[1][0] += a.y * b.x; acc[1][1] += a.y * b.y; acc[1][2] += a.y * b.z; acc[1][3] += a.y * b.w;
      acc[2][0] += a.z * b.x; acc[2][1] += a.z * b.y; acc[2][2] += a.z * b.z; acc[2][3] += a.z * b.w;
      acc[3][0] += a.w * b.x; acc[3][1] += a.w * b.y; acc[3][2] += a.w * b.z; acc[3][3] += a.w * b.w;
    }
  }
#pragma unroll
  for (int ii = 0; ii < 4; ii++) {
    int m = m0 + ty * 4 + ii;
#pragma unroll
    for (int jj = 0; jj < 4; jj++) {
      int n = n0 + tx * 4 + jj;
      if (n >= N) continue;
      float v = acc[ii][jj] + bias[n];
      if (EPI == 1) v = 0.5f * v * (1.f + erff(v * 0.70710678118f));
      if (EPI == 2) v += resid[(size_t)m * N + n];
      if (EPI == 3) {
        int b = m >> 9, l = m & 511;
        v += pos[(size_t)l * 1024 + n] + ltw[n] * lead[b] + ltb[n];
      }
      C[(size_t)m * N + n] = v;
    }
  }
}

// ---------------------------------------------------------------------------
// LayerNorm over D=1024 (grid M). In-place safe.
// ---------------------------------------------------------------------------
__global__ __launch_bounds__(256) void k_ln(
    const float* __restrict__ src, const float* __restrict__ add,
    const float* __restrict__ g, const float* __restrict__ bb,
    float* __restrict__ dst) {
  __shared__ float red[8];
  int m = blockIdx.x, tid = threadIdx.x;
  float4 x = *(const float4*)(src + (size_t)m * 1024 + tid * 4);
  if (add) {
    float4 a2 = *(const float4*)(add + (size_t)m * 1024 + tid * 4);
    x.x += a2.x; x.y += a2.y; x.z += a2.z; x.w += a2.w;
  }
  float s1 = x.x + x.y + x.z + x.w;
  float s2 = x.x * x.x + x.y * x.y + x.z * x.z + x.w * x.w;
  for (int off = 1; off < 64; off <<= 1) {
    s1 += __shfl_xor(s1, off); s2 += __shfl_xor(s2, off);
  }
  if ((tid & 63) == 0) { red[(tid >> 6) * 2] = s1; red[(tid >> 6) * 2 + 1] = s2; }
  __syncthreads();
  s1 = red[0] + red[2] + red[4] + red[6];
  s2 = red[1] + red[3] + red[5] + red[7];
  float mean = s1 * (1.f / 1024.f);
  float var = s2 * (1.f / 1024.f) - mean * mean;
  float rstd = rsqrtf(var + EPSF);
  int c = tid * 4;
  float4 o;
  o.x = (x.x - mean) * rstd * g[c + 0] + bb[c + 0];
  o.y = (x.y - mean) * rstd * g[c + 1] + bb[c + 1];
  o.z = (x.z - mean) * rstd * g[c + 2] + bb[c + 2];
  o.w = (x.w - mean) * rstd * g[c + 3] + bb[c + 3];
  *(float4*)(dst + (size_t)m * 1024 + c) = o;
}

// ---------------------------------------------------------------------------
// Patch attention: per (b,h,ntile16). Two-pass softmax with S in LDS.
// ---------------------------------------------------------------------------
__global__ __launch_bounds__(256) void k_attn(
    const float* __restrict__ qkv, float* __restrict__ o) {
  __shared__ float Q[16][68];
  __shared__ float S[16][516];
  __shared__ float KV[32][68];
  int bid = blockIdx.x;
  int nt = bid & 31, h = (bid >> 5) & 15, b = bid >> 9;
  int tid = threadIdx.x;
  for (int i = tid; i < 16 * 64; i += 256) {
    int r = i >> 6, e = i & 63;
    Q[r][e] = qkv[(size_t)(b * 512 + nt * 16 + r) * 3072 + h * 64 + e];
  }
  __syncthreads();
  int r = tid >> 4, lane = tid & 15;
  for (int kt = 0; kt < 16; kt++) {
    for (int i = tid; i < 32 * 64; i += 256) {
      int rr = i >> 6, e = i & 63;
      KV[rr][e] = qkv[(size_t)(b * 512 + kt * 32 + rr) * 3072 + 1024 + h * 64 + e];
    }
    __syncthreads();
    for (int jj = lane; jj < 32; jj += 16) {
      float acc = 0.f;
#pragma unroll 8
      for (int e = 0; e < 64; e++) acc += Q[r][e] * KV[jj][e];
      S[r][kt * 32 + jj] = acc * 0.125f;
    }
    __syncthreads();
  }
  float mx = -1e30f;
  for (int j = lane; j < 512; j += 16) mx = fmaxf(mx, S[r][j]);
  for (int off = 1; off < 16; off <<= 1) mx = fmaxf(mx, __shfl_xor(mx, off));
  float sum = 0.f;
  for (int j = lane; j < 512; j += 16) {
    float e = __expf(S[r][j] - mx);
    S[r][j] = e; sum += e;
  }
  sum = red16(sum);
  float inv = 1.f / sum;
  int e0 = lane * 4;
  float4 accv = {0.f, 0.f, 0.f, 0.f};
  for (int kt = 0; kt < 16; kt++) {
    __syncthreads();
    for (int i = tid; i < 32 * 64; i += 256) {
      int rr = i >> 6, e = i & 63;
      KV[rr][e] = qkv[(size_t)(b * 512 + kt * 32 + rr) * 3072 + 2048 + h * 64 + e];
    }
    __syncthreads();
#pragma unroll 8
    for (int j = 0; j < 32; j++) {
      float p = S[r][kt * 32 + j] * inv;
      accv.x += p * KV[j][e0 + 0]; accv.y += p * KV[j][e0 + 1];
      accv.z += p * KV[j][e0 + 2]; accv.w += p * KV[j][e0 + 3];
    }
  }
  float* op = o + (size_t)(b * 512 + nt * 16 + r) * 1024 + h * 64 + e0;
  op[0] = accv.x; op[1] = accv.y; op[2] = accv.z; op[3] = accv.w;
}

// ---------------------------------------------------------------------------
// ODE v13 kernels: fence-free kernel-per-phase pipeline.
// swz/swz8: bf16 activation images pre-swizzled per 16-token group (v9 layout)
// ---------------------------------------------------------------------------
__device__ __forceinline__ int swz(int m, int c) {
  int g = c >> 3;
  g = (g & ~7) | ((g ^ m) & 7);
  return m * 1024 + g * 8 + (c & 7);
}
__device__ __forceinline__ int swz8(int m, int k) {  // k multiple of 8
  int g = k >> 3;
  g = (g & ~7) | ((g ^ m) & 7);
  return m * 1024 + g * 8;
}

// GEMM phase kernel. Grid 256 = 64 token-groups x 4 col-slices, 16 waves.
// PASS 1: h_img[swz] = bf16(relu(src@w1^T + b1))
// PASS 2: zraw[token][col] = f32(src@w2^T)   (bias/resid applied in k_rk4)
template <int PASS>
__global__ __launch_bounds__(1024) void k_og(
    const u16* __restrict__ wp, const float* __restrict__ bias,
    const u16* __restrict__ src_img, u16* __restrict__ h_img,
    float* __restrict__ zraw) {
  __shared__ __align__(16) u16 bufA[16 * 1024];
  int tid = threadIdx.x;
  int bid = blockIdx.x;
  int g = bid >> 2, cg = bid & 3;
  int wvid = tid >> 6, lane = tid & 63;
  int row16 = lane & 15, quad = lane >> 4;
  int n = cg * 256 + wvid * 16 + row16;  // this lane's output column
  int ct = cg * 16 + wvid;               // global col-tile 0..63
  const u16* wb = wp + ((size_t)ct * 2048 + lane) * 8;  // packed frag base
  // ---- stage activation image (32KB) -> LDS (per-lane src, linear dst) ----
  {
    const u16* src = src_img + (size_t)g * 16384 + wvid * 1024 + lane * 8;
    u16* dst = bufA + wvid * 1024;
    __builtin_amdgcn_global_load_lds(
        (const __attribute__((address_space(1))) uint32_t*)src,
        (__attribute__((address_space(3))) uint32_t*)dst, 16, 0, 0);
    __builtin_amdgcn_global_load_lds(
        (const __attribute__((address_space(1))) uint32_t*)(src + 512),
        (__attribute__((address_space(3))) uint32_t*)(dst + 512), 16, 0, 0);
  }
  VMCNT(0);
  __syncthreads();
  // ---- MFMA K-loop (v9-verified fragment path) ----
  f32x4 acc = {0.f, 0.f, 0.f, 0.f};
#pragma unroll
  for (int kk = 0; kk < 32; kk++) {
    bf16x8 wf = *(const bf16x8*)(wb + kk * 512);
    bf16x8 aF = *(const bf16x8*)(bufA + swz8(row16, kk * 32 + quad * 8));
    acc = __builtin_amdgcn_mfma_f32_16x16x32_bf16(aF, wf, acc, 0, 0, 0);
  }
  if (PASS == 1) {
    float bv = bias[n];
#pragma unroll
    for (int r = 0; r < 4; r++) {
      int ml = quad * 4 + r;
      h_img[(size_t)g * 16384 + swz(ml, n)] = f2b(fmaxf(acc[r] + bv, 0.f));
    }
  } else {
#pragma unroll
    for (int r = 0; r < 4; r++) {
      int tok = g * 16 + quad * 4 + r;
      zraw[(size_t)tok * 1024 + n] = acc[r];
    }
  }
}

// Init: y = nvf = xs; act image = bf16(xs); out = xs. Grid 1024 (token/block).
__global__ __launch_bounds__(256) void k_odeinit(
    const float* __restrict__ xs, float* __restrict__ y,
    float* __restrict__ nvf, u16* __restrict__ act_img,
    float* __restrict__ out) {
  int t = blockIdx.x, tid = threadIdx.x;
  int c = tid * 4;
  int g = t >> 4, ml = t & 15;
  float4 v = *(const float4*)(xs + (size_t)t * 1024 + c);
  *(float4*)(y + (size_t)t * 1024 + c) = v;
  *(float4*)(nvf + (size_t)t * 1024 + c) = v;
  *(float4*)(out + (size_t)t * 1024 + c) = v;
  u16* ag = act_img + (size_t)g * 16384;
  ag[swz(ml, c + 0)] = f2b(v.x); ag[swz(ml, c + 1)] = f2b(v.y);
  ag[swz(ml, c + 2)] = f2b(v.z); ag[swz(ml, c + 3)] = f2b(v.w);
}

// RK4 + LN epilogue. Grid 1024 (token/block), 256 thr.
// z = zraw + b2 + nvf; row-LN(z) -> k; RK4 state update; write next act img.
__global__ __launch_bounds__(256) void k_rk4(
    const float* __restrict__ zraw, const float* __restrict__ b2,
    const float* __restrict__ ng, const float* __restrict__ nb,
    float* __restrict__ y, float* __restrict__ accr,
    float* __restrict__ nvf, u16* __restrict__ act_img,
    float* __restrict__ out, const float* __restrict__ lead,
    int s, int ph) {
  __shared__ float red[8];
  int t = blockIdx.x, tid = threadIdx.x;
  int c = tid * 4;
  int g = t >> 4, ml = t & 15;
  float4 zr = *(const float4*)(zraw + (size_t)t * 1024 + c);
  float4 bb = *(const float4*)(b2 + c);
  float4 nv = *(const float4*)(nvf + (size_t)t * 1024 + c);
  float z0 = zr.x + bb.x + nv.x, z1 = zr.y + bb.y + nv.y;
  float z2 = zr.z + bb.z + nv.z, z3 = zr.w + bb.w + nv.w;
  float s1 = z0 + z1 + z2 + z3;
  float s2 = z0 * z0 + z1 * z1 + z2 * z2 + z3 * z3;
  for (int off = 1; off < 64; off <<= 1) {
    s1 += __shfl_xor(s1, off); s2 += __shfl_xor(s2, off);
  }
  if ((tid & 63) == 0) { red[(tid >> 6) * 2] = s1; red[(tid >> 6) * 2 + 1] = s2; }
  __syncthreads();
  s1 = red[0] + red[2] + red[4] + red[6];
  s2 = red[1] + red[3] + red[5] + red[7];
  float mean = s1 * (1.f / 1024.f);
  float var = s2 * (1.f / 1024.f) - mean * mean;
  float rstd = rsqrtf(var + EPSF);
  float4 gv = *(const float4*)(ng + c);
  float4 bv = *(const float4*)(nb + c);
  float k0 = (z0 - mean) * rstd * gv.x + bv.x;
  float k1 = (z1 - mean) * rstd * gv.y + bv.y;
  float k2 = (z2 - mean) * rstd * gv.z + bv.z;
  float k3 = (z3 - mean) * rstd * gv.w + bv.w;
  float4 yv = *(const float4*)(y + (size_t)t * 1024 + c);
  float4 ac;
  float cf = (ph < 2) ? 0.5f * RESF : RESF;
  const float h6 = RESF / 6.0f;
  float4 nn;
  if (ph == 0) {
    ac.x = k0; ac.y = k1; ac.z = k2; ac.w = k3;
    nn.x = yv.x + cf * k0; nn.y = yv.y + cf * k1;
    nn.z = yv.z + cf * k2; nn.w = yv.w + cf * k3;
    *(float4*)(accr + (size_t)t * 1024 + c) = ac;
  } else if (ph < 3) {
    ac = *(const float4*)(accr + (size_t)t * 1024 + c);
    ac.x += 2.f * k0; ac.y += 2.f * k1; ac.z += 2.f * k2; ac.w += 2.f * k3;
    nn.x = yv.x + cf * k0; nn.y = yv.y + cf * k1;
    nn.z = yv.z + cf * k2; nn.w = yv.w + cf * k3;
    *(float4*)(accr + (size_t)t * 1024 + c) = ac;
  } else {
    ac = *(const float4*)(accr + (size_t)t * 1024 + c);
    yv.x += h6 * (ac.x + k0); yv.y += h6 * (ac.y + k1);
    yv.z += h6 * (ac.z + k2); yv.w += h6 * (ac.w + k3);
    nn = yv;
    *(float4*)(y + (size_t)t * 1024 + c) = yv;
    int idxb = (int)roundf(lead[t >> 9] * 100.0f);
    if ((s + 1) == idxb)
      *(float4*)(out + (size_t)t * 1024 + c) = yv;
  }
  *(float4*)(nvf + (size_t)t * 1024 + c) = nn;
  u16* ag = act_img + (size_t)g * 16384;
  ag[swz(ml, c + 0)] = f2b(nn.x); ag[swz(ml, c + 1)] = f2b(nn.y);
  ag[swz(ml, c + 2)] = f2b(nn.z); ag[swz(ml, c + 3)] = f2b(nn.w);
}

// ---------------------------------------------------------------------------
// Unpatchify: y3[m][p*10+q*5+c] -> out[b][c][hh*2+p][ww*2+q], FLOAT32
// ---------------------------------------------------------------------------
__global__ __launch_bounds__(256) void k_unpatch(
    const float* __restrict__ y3, float* __restrict__ outp) {
  int o = blockIdx.x * 256 + threadIdx.x;
  if (o >= 20480) return;
  int b = o / 10240;
  int c = (o / 2048) % 5;
  int hrow = (o / 64) % 32;
  int wcol = o % 64;
  int hh = hrow >> 1, p = hrow & 1, ww = wcol >> 1, q = wcol & 1;
  int m2 = b * 512 + hh * 32 + ww;
  int colj = p * 10 + q * 5 + c;
  outp[o] = y3[(size_t)m2 * 20 + colj];
}

// ===========================================================================
extern "C" void kernel_launch(void* const* d_in, const int* in_sizes, int n_in,
                              void* d_out, int out_size, void* d_ws, size_t ws_size,
                              hipStream_t stream) {
  const float* x         = (const float*)d_in[0];
  const float* lead      = (const float*)d_in[1];
  const float* patch_w   = (const float*)d_in[2];
  const float* patch_b   = (const float*)d_in[3];
  const float* var_embed = (const float*)d_in[4];
  const float* var_query = (const float*)d_in[5];
  const float* agg_in_w  = (const float*)d_in[6];
  const float* agg_in_b  = (const float*)d_in[7];
  const float* agg_out_w = (const float*)d_in[8];
  const float* agg_out_b = (const float*)d_in[9];
  const float* pos_embed = (const float*)d_in[10];
  const float* lt_w      = (const float*)d_in[11];
  const float* lt_b      = (const float*)d_in[12];
  const float* blk_qkv_w = (const float*)d_in[13];
  const float* blk_qkv_b = (const float*)d_in[14];
  const float* blk_out_w = (const float*)d_in[15];
  const float* blk_out_b = (const float*)d_in[16];
  const float* blk_n1_g  = (const float*)d_in[17];
  const float* blk_n1_b  = (const float*)d_in[18];
  const float* blk_n2_g  = (const float*)d_in[19];
  const float* blk_n2_b  = (const float*)d_in[20];
  const float* ode_w1    = (const float*)d_in[21];
  const float* ode_b1    = (const float*)d_in[22];
  const float* ode_w2    = (const float*)d_in[23];
  const float* ode_b2    = (const float*)d_in[24];
  const float* ode_ng    = (const float*)d_in[25];
  const float* ode_nb    = (const float*)d_in[26];
  const float* norm_g    = (const float*)d_in[27];
  const float* norm_b    = (const float*)d_in[28];
  const float* h1_w      = (const float*)d_in[29];
  const float* h1_b      = (const float*)d_in[30];
  const float* h2_w      = (const float*)d_in[31];
  const float* h2_b      = (const float*)d_in[32];
  const float* hf_w      = (const float*)d_in[33];
  const float* hf_b      = (const float*)d_in[34];
  (void)in_sizes; (void)n_in; (void)out_size; (void)ws_size;

  float* ws = (float*)d_ws;
  // ODE buffers in ode-dead regions (qkv/attno/t1):
  u16*   act16 = (u16*)(ws + 0);        // 2MB act image
  u16*   h16   = (u16*)(ws + 524288);   // 2MB h image
  float* zraw  = ws + 1048576;          // 4MB raw GEMM2 out
  float* ybuf  = ws + 2097152;          // 4MB RK4 y      (end 3145728)
  float* accr  = ws + 3145728;          // 4MB RK4 accum  (attno region)
  float* nvf   = ws + 4194304;          // 4MB f32 act    (t1 region)
  float* patches = ws + 0;         // 20480 (stage-1 only; dead before ode)
  float* qvec    = ws + 20480;     // 1024
  float* qb      = ws + 21504;     // 256 (16 used)
  float* u       = ws + 21760;     // 16384
  float* PU      = ws + 38144;     // 320
  float* C0      = ws + 38464;     // 80 (pad to 40960)
  float* amat    = ws + 40960;     // 81920
  float* PW      = ws + 122880;    // 20480
  float* CV      = ws + 143360;    // 5120  (end 148480)
  float* agg     = ws + 3145728;   // 1048576 (attno slot; dead by then)
  float* qkv   = ws + 0;           // 3145728
  float* attno = ws + 3145728;     // 1048576
  float* t1    = ws + 4194304;     // 1048576
  float* odeo  = ws + 5242880;     // 1048576
  float* xs    = ws + 6291456;     // 1048576
  u16*   w16a  = (u16*)(ws + 7340032);  // packed w1 (bf16 frag blob)
  u16*   w16b  = (u16*)(ws + 7864320);  // packed w2
  float* y1 = ws + 0;
  float* y2 = ws + 1048576;
  float* y3 = ws + 2097152;        // 20480

  // ---- stage 1 ----
  k_patches<<<dim3(80), dim3(256), 0, stream>>>(x, patches);
  k_qvec<<<dim3(64), dim3(256), 0, stream>>>(var_query, agg_in_w, agg_in_b, qvec);
  k_qb<<<dim3(1), dim3(256), 0, stream>>>(qvec, agg_in_b + 1024, qb);
  k_u<<<dim3(64), dim3(256), 0, stream>>>(qvec, agg_in_w + (size_t)1024 * 1024, u);
  k_pu<<<dim3(80), dim3(256), 0, stream>>>(patch_w, patch_b, var_embed, u, qb, PU, C0);
  k_pw<<<dim3(5120), dim3(256), 0, stream>>>(
      agg_in_w + (size_t)2048 * 1024, agg_in_b + 2048, patch_w, patch_b,
      var_embed, PW, CV);
  k_scoresm<<<dim3(1024), dim3(256), 0, stream>>>(patches, PU, C0, amat);
  k_agg<<<dim3(1024), dim3(256), 0, stream>>>(patches, PW, CV, amat, agg);
  k_gemm<3><<<dim3(16, 16), dim3(256), 0, stream>>>(
      agg, agg_out_w, agg_out_b, xs, 1024, 1024, 1024,
      nullptr, pos_embed, lt_w, lt_b, lead);

  // ---- transformer blocks ----
  for (int i = 0; i < 2; i++) {
    k_gemm<0><<<dim3(48, 16), dim3(256), 0, stream>>>(
        xs, blk_qkv_w + (size_t)i * 3072 * 1024, blk_qkv_b + i * 3072, qkv,
        1024, 3072, 1024, nullptr, nullptr, nullptr, nullptr, nullptr);
    k_attn<<<dim3(1024), dim3(256), 0, stream>>>(qkv, attno);
    k_gemm<2><<<dim3(16, 16), dim3(256), 0, stream>>>(
        attno, blk_out_w + (size_t)i * 1048576, blk_out_b + i * 1024, t1,
        1024, 1024, 1024, xs, nullptr, nullptr, nullptr, nullptr);
    k_ln<<<dim3(1024), dim3(256), 0, stream>>>(
        t1, (const float*)nullptr, blk_n1_g + i * 1024, blk_n1_b + i * 1024, xs);
    k_pack<<<dim3(4096), dim3(256), 0, stream>>>(
        ode_w1 + (size_t)i * 1048576, w16a);
    k_pack<<<dim3(4096), dim3(256), 0, stream>>>(
        ode_w2 + (size_t)i * 1048576, w16b);
    // ---- fence-free ODE: 3 kernels per RK4 phase ----
    k_odeinit<<<dim3(1024), dim3(256), 0, stream>>>(xs, ybuf, nvf, act16, odeo);
    for (int s = 0; s < NSTEPS; s++) {
      for (int ph = 0; ph < 4; ph++) {
        k_og<1><<<dim3(256), dim3(1024), 0, stream>>>(
            w16a, ode_b1 + i * 1024, act16, h16, nullptr);
        k_og<2><<<dim3(256), dim3(1024), 0, stream>>>(
            w16b, nullptr, h16, nullptr, zraw);
        k_rk4<<<dim3(1024), dim3(256), 0, stream>>>(
            zraw, ode_b2 + i * 1024, ode_ng + i * 1024, ode_nb + i * 1024,
            ybuf, accr, nvf, act16, odeo, lead, s, ph);
      }
    }
    k_ln<<<dim3(1024), dim3(256), 0, stream>>>(
        xs, odeo, blk_n2_g + i * 1024, blk_n2_b + i * 1024, xs);
  }

  // ---- head ----
  k_ln<<<dim3(1024), dim3(256), 0, stream>>>(
      xs, (const float*)nullptr, norm_g, norm_b, xs);
  k_gemm<1><<<dim3(16, 16), dim3(256), 0, stream>>>(
      xs, h1_w, h1_b, y1, 1024, 1024, 1024, nullptr, nullptr, nullptr, nullptr, nullptr);
  k_gemm<1><<<dim3(16, 16), dim3(256), 0, stream>>>(
      y1, h2_w, h2_b, y2, 1024, 1024, 1024, nullptr, nullptr, nullptr, nullptr, nullptr);
  k_gemm<0><<<dim3(1, 16), dim3(256), 0, stream>>>(
      y2, hf_w, hf_b, y3, 1024, 20, 1024, nullptr, nullptr, nullptr, nullptr, nullptr);
  k_unpatch<<<dim3(80), dim3(256), 0, stream>>>(y3, (float*)d_out);
}

// Round 11
// 2763.272 us; speedup vs baseline: 5.0851x; 1.1311x over previous
//
#include <hip/hip_runtime.h>
#include <stdint.h>

// ============================================================================
// ConViTCast: B=2 V=5 H=32 W=64 P=2 D=1024 NH=16 hd=64 DEPTH=2 L=512 BL=1024
// R10 this session: v14 — v13 (fence-free ODE pipeline, 14.05->3.13ms WIN)
// + bf16-MFMA conversion of the big fp32 GEMMs (qkv, attn-out, h1, h2) via
// k_mg, modeled byte-for-byte on the verified k_og fragment path. A-operand
// staged in-kernel (f32 rows -> f2b -> swz LDS, v7-verified layout) so no
// activation images are needed. Weight blobs packed by the existing k_pack
// into ode-dead workspace (lifetimes checked: qkv blob in attno+t1 dead
// until attn/attn-out write; attn-out blob in odeo dead until ODE init;
// h1/h2 blob in attno region during head). agg-out + hf stay fp32.
// Rejected alternative: fusing k_rk4 into k_og<1> — 4x duplicated full-row
// reads (64MB/phase cross-XCD) cost more than the saved launch.
// Predict: total 3.13 -> ~2.7-2.8ms; absmax 9.77e-4 -> 2-6e-3 (bf16 attn
// path). If tolerance fails: revert to v13, take safe fp32 tiling instead.
// ============================================================================

#define NSTEPS 10
#define RESF 0.01f
#define EPSF 1e-5f

typedef unsigned short u16;
typedef unsigned int u32;
typedef __attribute__((ext_vector_type(8))) short bf16x8;
typedef __attribute__((ext_vector_type(4))) float f32x4;

// s_waitcnt vmcnt(N), ignore exp/lgkm (gfx9 encoding: vm[3:0]|[15:14], exp=7, lgkm=15)
#define VMCNT(N) __builtin_amdgcn_s_waitcnt(0x0F70 | ((N) & 0xF) | ((((N) >> 4) & 0x3) << 14))

__device__ __forceinline__ float b2f(u16 u) {
  return __uint_as_float(((uint32_t)u) << 16);
}
__device__ __forceinline__ u16 f2b(float f) {
  uint32_t x = __float_as_uint(f);
  uint32_t r = x + 0x7fffu + ((x >> 16) & 1u);  // round-to-nearest-even
  return (u16)(r >> 16);
}
__device__ __forceinline__ float red16(float v) {
  v += __shfl_xor(v, 1); v += __shfl_xor(v, 2);
  v += __shfl_xor(v, 4); v += __shfl_xor(v, 8);
  return v;
}

// Repack f32 weight [Ncols][1024 k] -> bf16 MFMA-frag blob (grid = N*4 blocks):
// blob[((ct*32+kk)*64+l)*8+j] = w[ct*16+(l&15)][kk*32+(l>>4)*8+j]
__global__ __launch_bounds__(256) void k_pack(
    const float* __restrict__ in, u16* __restrict__ out16) {
  int i = blockIdx.x * 256 + threadIdx.x;
  int j = i & 7;
  int l = (i >> 3) & 63;
  int kk = (i >> 9) & 31;
  int ct = i >> 14;
  int col = ct * 16 + (l & 15);
  int k = kk * 32 + ((l >> 4) << 3) + j;
  out16[i] = f2b(in[(size_t)col * 1024 + k]);
}

// ---------------------------------------------------------------------------
// Extract patches[m*20 + v*4 + p] from x[b,v,h,w]; m=b*512+l, l=hh*32+ww
// ---------------------------------------------------------------------------
__global__ __launch_bounds__(256) void k_patches(
    const float* __restrict__ x, float* __restrict__ patches) {
  int i = blockIdx.x * 256 + threadIdx.x;  // grid 80*256 = 20480
  int m = i / 20, r = i % 20;
  int v = r >> 2, p = r & 3;
  int b = m >> 9, l = m & 511;
  int hh = l >> 5, ww = l & 31;
  int pr = p >> 1, pc = p & 1;
  patches[i] = x[((size_t)(b * 5 + v) * 32 + hh * 2 + pr) * 64 + ww * 2 + pc];
}

// qvec = var_query @ Wq^T + bq   (grid 64)
__global__ __launch_bounds__(256) void k_qvec(
    const float* __restrict__ vq, const float* __restrict__ w,
    const float* __restrict__ bias, float* __restrict__ qvec) {
  int dq = blockIdx.x * 16 + (threadIdx.x >> 4);
  int lane = threadIdx.x & 15;
  float p = 0.f;
  for (int j = 0; j < 64; j++) {
    int d = lane + 16 * j;
    p += vq[d] * w[(size_t)dq * 1024 + d];
  }
  p = red16(p);
  if (lane == 0) qvec[dq] = p + bias[dq];
}

// qb[h] = sum_e qvec[h*64+e]*bk[h*64+e]   (grid 1)
__global__ __launch_bounds__(256) void k_qb(
    const float* __restrict__ qvec, const float* __restrict__ bk,
    float* __restrict__ qb) {
  int h = threadIdx.x >> 4, lane = threadIdx.x & 15;
  float p = 0.f;
  for (int e = lane; e < 64; e += 16) p += qvec[h * 64 + e] * bk[h * 64 + e];
  p = red16(p);
  if (lane == 0) qb[h] = p;
}

// u[h][d] = sum_e qvec[h*64+e] * Wk[h*64+e][d]   (grid 64)
__global__ __launch_bounds__(256) void k_u(
    const float* __restrict__ qvec, const float* __restrict__ wk,
    float* __restrict__ u) {
  int d = blockIdx.x * 16 + (threadIdx.x & 15);
  int h = threadIdx.x >> 4;
  float acc = 0.f;
  for (int e = 0; e < 64; e++)
    acc += qvec[h * 64 + e] * wk[(size_t)(h * 64 + e) * 1024 + d];
  u[h * 1024 + d] = acc;
}

// PU[(v*16+h)*4+p] = 0.125*sum_d pw[v,d,p]*u[h,d]
// C0[v*16+h]       = 0.125*(sum_d (pb+ve)[v,d]*u[h,d] + qb[h])     (grid 80)
__global__ __launch_bounds__(256) void k_pu(
    const float* __restrict__ pw, const float* __restrict__ pb,
    const float* __restrict__ ve, const float* __restrict__ u,
    const float* __restrict__ qb, float* __restrict__ PU,
    float* __restrict__ C0) {
  int v = blockIdx.x / 16, h = blockIdx.x % 16;
  int t = threadIdx.x;
  float a0 = 0, a1 = 0, a2 = 0, a3 = 0, ac = 0;
  for (int d = t; d < 1024; d += 256) {
    float uu = u[h * 1024 + d];
    const float* p4 = pw + ((size_t)v * 1024 + d) * 4;
    a0 += p4[0] * uu; a1 += p4[1] * uu; a2 += p4[2] * uu; a3 += p4[3] * uu;
    ac += (pb[v * 1024 + d] + ve[v * 1024 + d]) * uu;
  }
  for (int off = 1; off < 64; off <<= 1) {
    a0 += __shfl_xor(a0, off); a1 += __shfl_xor(a1, off);
    a2 += __shfl_xor(a2, off); a3 += __shfl_xor(a3, off);
    ac += __shfl_xor(ac, off);
  }
  __shared__ float r[4][5];
  if ((t & 63) == 0) {
    int w = t >> 6;
    r[w][0] = a0; r[w][1] = a1; r[w][2] = a2; r[w][3] = a3; r[w][4] = ac;
  }
  __syncthreads();
  if (t == 0) {
    float s[5];
    for (int j = 0; j < 5; j++) s[j] = r[0][j] + r[1][j] + r[2][j] + r[3][j];
    float* pu = PU + (v * 16 + h) * 4;
    pu[0] = 0.125f * s[0]; pu[1] = 0.125f * s[1];
    pu[2] = 0.125f * s[2]; pu[3] = 0.125f * s[3];
    C0[v * 16 + h] = 0.125f * (s[4] + qb[h]);
  }
}

// PW[(v*1024+col)*4+p] = sum_d Wv[col,d]*pw[v,d,p]
// CV[v*1024+col]       = sum_d Wv[col,d]*(pb+ve)[v,d] + bv[col]    (grid 5120)
__global__ __launch_bounds__(256) void k_pw(
    const float* __restrict__ wv, const float* __restrict__ bv,
    const float* __restrict__ pw, const float* __restrict__ pb,
    const float* __restrict__ ve, float* __restrict__ PW,
    float* __restrict__ CV) {
  int v = blockIdx.x >> 10, col = blockIdx.x & 1023;
  int t = threadIdx.x;
  const float* wr = wv + (size_t)col * 1024;
  float4 w4 = *(const float4*)(wr + t * 4);
  float a0 = 0, a1 = 0, a2 = 0, a3 = 0, ac = 0;
#pragma unroll
  for (int j = 0; j < 4; j++) {
    int d = t * 4 + j;
    float wj = (j == 0) ? w4.x : (j == 1) ? w4.y : (j == 2) ? w4.z : w4.w;
    const float* p4 = pw + ((size_t)v * 1024 + d) * 4;
    a0 += wj * p4[0]; a1 += wj * p4[1]; a2 += wj * p4[2]; a3 += wj * p4[3];
    ac += wj * (pb[v * 1024 + d] + ve[v * 1024 + d]);
  }
  for (int off = 1; off < 64; off <<= 1) {
    a0 += __shfl_xor(a0, off); a1 += __shfl_xor(a1, off);
    a2 += __shfl_xor(a2, off); a3 += __shfl_xor(a3, off);
    ac += __shfl_xor(ac, off);
  }
  __shared__ float r[4][5];
  if ((t & 63) == 0) {
    int w = t >> 6;
    r[w][0] = a0; r[w][1] = a1; r[w][2] = a2; r[w][3] = a3; r[w][4] = ac;
  }
  __syncthreads();
  if (t == 0) {
    float s[5];
    for (int j = 0; j < 5; j++) s[j] = r[0][j] + r[1][j] + r[2][j] + r[3][j];
    float* o = PW + ((size_t)(v * 1024 + col)) * 4;
    o[0] = s[0]; o[1] = s[1]; o[2] = s[2]; o[3] = s[3];
    CV[v * 1024 + col] = s[4] + bv[col];
  }
}

// scores s[v][h] = patches[m,v]·PU[v,h] + C0[v,h]; softmax over v
// -> amat[m*80 + h*5 + v]                                          (grid 1024)
__global__ __launch_bounds__(256) void k_scoresm(
    const float* __restrict__ patches, const float* __restrict__ PU,
    const float* __restrict__ C0, float* __restrict__ amat) {
  __shared__ float pat[20];
  __shared__ float sa[16][8];
  int m = blockIdx.x, t = threadIdx.x;
  if (t < 20) pat[t] = patches[m * 20 + t];
  __syncthreads();
  if (t < 80) {
    int v = t / 16, h = t % 16;
    const float* pu = PU + (v * 16 + h) * 4;
    float s = C0[v * 16 + h] + pat[v * 4 + 0] * pu[0] + pat[v * 4 + 1] * pu[1]
            + pat[v * 4 + 2] * pu[2] + pat[v * 4 + 3] * pu[3];
    sa[h][v] = s;
  }
  __syncthreads();
  if (t < 16) {
    float mx = sa[t][0];
    for (int v = 1; v < 5; v++) mx = fmaxf(mx, sa[t][v]);
    float e[5], sum = 0.f;
    for (int v = 0; v < 5; v++) { e[v] = __expf(sa[t][v] - mx); sum += e[v]; }
    float inv = 1.f / sum;
    for (int v = 0; v < 5; v++) amat[m * 80 + t * 5 + v] = e[v] * inv;
  }
}

// agg[m,c] = sum_v amat[m,h(c),v] * (patches[m,v]·PW[v,c] + CV[v,c]) (grid 1024)
__global__ __launch_bounds__(256) void k_agg(
    const float* __restrict__ patches, const float* __restrict__ PW,
    const float* __restrict__ CV, const float* __restrict__ amat,
    float* __restrict__ agg) {
  __shared__ float pat[20];
  __shared__ float am[80];
  int m = blockIdx.x, t = threadIdx.x;
  if (t < 20) pat[t] = patches[m * 20 + t];
  if (t < 80) am[t] = amat[m * 80 + t];
  __syncthreads();
  int c0 = t * 4;
#pragma unroll
  for (int j = 0; j < 4; j++) {
    int c = c0 + j;
    int h = c >> 6;
    float acc = 0.f;
#pragma unroll
    for (int v = 0; v < 5; v++) {
      float4 w4 = *(const float4*)(PW + ((size_t)(v * 1024 + c)) * 4);
      float val = pat[v * 4 + 0] * w4.x + pat[v * 4 + 1] * w4.y
                + pat[v * 4 + 2] * w4.z + pat[v * 4 + 3] * w4.w
                + CV[v * 1024 + c];
      acc += am[h * 5 + v] * val;
    }
    agg[(size_t)m * 1024 + c] = acc;
  }
}

// ---------------------------------------------------------------------------
// Generic fp32 GEMM (kept for agg-out EPI3 and hf N=20):
// C[M][N] = A[M][K] @ W[N][K]^T + bias. EPI: 0 plain, 1 gelu, 2 +resid, 3 +pos
// ---------------------------------------------------------------------------
template <int EPI>
__global__ __launch_bounds__(256) void k_gemm(
    const float* __restrict__ A, const float* __restrict__ W,
    const float* __restrict__ bias, float* __restrict__ C,
    int M, int N, int K,
    const float* __restrict__ resid,
    const float* __restrict__ pos, const float* __restrict__ ltw,
    const float* __restrict__ ltb, const float* __restrict__ lead) {
  __shared__ float As[16][68];
  __shared__ float Ws[16][68];
  int m0 = blockIdx.y * 64, n0 = blockIdx.x * 64;
  int tid = threadIdx.x;
  int tx = tid & 15, ty = tid >> 4;
  int lr = tid & 63, lk = (tid >> 6) * 4;
  float acc[4][4] = {};
  for (int k0 = 0; k0 < K; k0 += 16) {
    float4 av = *(const float4*)(A + (size_t)(m0 + lr) * K + k0 + lk);
    float4 wv = {0.f, 0.f, 0.f, 0.f};
    if (n0 + lr < N) {
      wv = *(const float4*)(W + (size_t)(n0 + lr) * K + k0 + lk);
    }
    __syncthreads();
    As[lk + 0][lr] = av.x; As[lk + 1][lr] = av.y;
    As[lk + 2][lr] = av.z; As[lk + 3][lr] = av.w;
    Ws[lk + 0][lr] = wv.x; Ws[lk + 1][lr] = wv.y;
    Ws[lk + 2][lr] = wv.z; Ws[lk + 3][lr] = wv.w;
    __syncthreads();
#pragma unroll
    for (int kk = 0; kk < 16; kk++) {
      float4 a = *(const float4*)&As[kk][ty * 4];
      float4 b = *(const float4*)&Ws[kk][tx * 4];
      acc[0][0] += a.x * b.x; acc[0][1] += a.x * b.y; acc[0][2] += a.x * b.z; acc[0][3] += a.x * b.w;
      acc[1][0] += a.y * b.x; acc[1][1] += a.y * b.y; acc[1][2] += a.y * b.z; acc[1][3] += a.y * b.w;
      acc[2][0] += a.z * b.x; acc[2][1] += a.z * b.y; acc[2][2] += a.z * b.z; acc[2][3] += a.z * b.w;
      acc[3][0] += a.w * b.x; acc[3][1] += a.w * b.y; acc[3][2] += a.w * b.z; acc[3][3] += a.w * b.w;
    }
  }
#pragma unroll
  for (int ii = 0; ii < 4; ii++) {
    int m = m0 + ty * 4 + ii;
#pragma unroll
    for (int jj = 0; jj < 4; jj++) {
      int n = n0 + tx * 4 + jj;
      if (n >= N) continue;
      float v = acc[ii][jj] + bias[n];
      if (EPI == 1) v = 0.5f * v * (1.f + erff(v * 0.70710678118f));
      if (EPI == 2) v += resid[(size_t)m * N + n];
      if (EPI == 3) {
        int b = m >> 9, l = m & 511;
        v += pos[(size_t)l * 1024 + n] + ltw[n] * lead[b] + ltb[n];
      }
      C[(size_t)m * N + n] = v;
    }
  }
}

// ---------------------------------------------------------------------------
// LayerNorm over D=1024 (grid M). In-place safe.
// ---------------------------------------------------------------------------
__global__ __launch_bounds__(256) void k_ln(
    const float* __restrict__ src, const float* __restrict__ add,
    const float* __restrict__ g, const float* __restrict__ bb,
    float* __restrict__ dst) {
  __shared__ float red[8];
  int m = blockIdx.x, tid = threadIdx.x;
  float4 x = *(const float4*)(src + (size_t)m * 1024 + tid * 4);
  if (add) {
    float4 a2 = *(const float4*)(add + (size_t)m * 1024 + tid * 4);
    x.x += a2.x; x.y += a2.y; x.z += a2.z; x.w += a2.w;
  }
  float s1 = x.x + x.y + x.z + x.w;
  float s2 = x.x * x.x + x.y * x.y + x.z * x.z + x.w * x.w;
  for (int off = 1; off < 64; off <<= 1) {
    s1 += __shfl_xor(s1, off); s2 += __shfl_xor(s2, off);
  }
  if ((tid & 63) == 0) { red[(tid >> 6) * 2] = s1; red[(tid >> 6) * 2 + 1] = s2; }
  __syncthreads();
  s1 = red[0] + red[2] + red[4] + red[6];
  s2 = red[1] + red[3] + red[5] + red[7];
  float mean = s1 * (1.f / 1024.f);
  float var = s2 * (1.f / 1024.f) - mean * mean;
  float rstd = rsqrtf(var + EPSF);
  int c = tid * 4;
  float4 o;
  o.x = (x.x - mean) * rstd * g[c + 0] + bb[c + 0];
  o.y = (x.y - mean) * rstd * g[c + 1] + bb[c + 1];
  o.z = (x.z - mean) * rstd * g[c + 2] + bb[c + 2];
  o.w = (x.w - mean) * rstd * g[c + 3] + bb[c + 3];
  *(float4*)(dst + (size_t)m * 1024 + c) = o;
}

// ---------------------------------------------------------------------------
// Patch attention: per (b,h,ntile16). Two-pass softmax with S in LDS.
// ---------------------------------------------------------------------------
__global__ __launch_bounds__(256) void k_attn(
    const float* __restrict__ qkv, float* __restrict__ o) {
  __shared__ float Q[16][68];
  __shared__ float S[16][516];
  __shared__ float KV[32][68];
  int bid = blockIdx.x;
  int nt = bid & 31, h = (bid >> 5) & 15, b = bid >> 9;
  int tid = threadIdx.x;
  for (int i = tid; i < 16 * 64; i += 256) {
    int r = i >> 6, e = i & 63;
    Q[r][e] = qkv[(size_t)(b * 512 + nt * 16 + r) * 3072 + h * 64 + e];
  }
  __syncthreads();
  int r = tid >> 4, lane = tid & 15;
  for (int kt = 0; kt < 16; kt++) {
    for (int i = tid; i < 32 * 64; i += 256) {
      int rr = i >> 6, e = i & 63;
      KV[rr][e] = qkv[(size_t)(b * 512 + kt * 32 + rr) * 3072 + 1024 + h * 64 + e];
    }
    __syncthreads();
    for (int jj = lane; jj < 32; jj += 16) {
      float acc = 0.f;
#pragma unroll 8
      for (int e = 0; e < 64; e++) acc += Q[r][e] * KV[jj][e];
      S[r][kt * 32 + jj] = acc * 0.125f;
    }
    __syncthreads();
  }
  float mx = -1e30f;
  for (int j = lane; j < 512; j += 16) mx = fmaxf(mx, S[r][j]);
  for (int off = 1; off < 16; off <<= 1) mx = fmaxf(mx, __shfl_xor(mx, off));
  float sum = 0.f;
  for (int j = lane; j < 512; j += 16) {
    float e = __expf(S[r][j] - mx);
    S[r][j] = e; sum += e;
  }
  sum = red16(sum);
  float inv = 1.f / sum;
  int e0 = lane * 4;
  float4 accv = {0.f, 0.f, 0.f, 0.f};
  for (int kt = 0; kt < 16; kt++) {
    __syncthreads();
    for (int i = tid; i < 32 * 64; i += 256) {
      int rr = i >> 6, e = i & 63;
      KV[rr][e] = qkv[(size_t)(b * 512 + kt * 32 + rr) * 3072 + 2048 + h * 64 + e];
    }
    __syncthreads();
#pragma unroll 8
    for (int j = 0; j < 32; j++) {
      float p = S[r][kt * 32 + j] * inv;
      accv.x += p * KV[j][e0 + 0]; accv.y += p * KV[j][e0 + 1];
      accv.z += p * KV[j][e0 + 2]; accv.w += p * KV[j][e0 + 3];
    }
  }
  float* op = o + (size_t)(b * 512 + nt * 16 + r) * 1024 + h * 64 + e0;
  op[0] = accv.x; op[1] = accv.y; op[2] = accv.z; op[3] = accv.w;
}

// ---------------------------------------------------------------------------
// swz/swz8: bf16 LDS tile layout (v7/v9-verified), per 16-token group.
// ---------------------------------------------------------------------------
__device__ __forceinline__ int swz(int m, int c) {
  int g = c >> 3;
  g = (g & ~7) | ((g ^ m) & 7);
  return m * 1024 + g * 8 + (c & 7);
}
__device__ __forceinline__ int swz8(int m, int k) {  // k multiple of 8
  int g = k >> 3;
  g = (g & ~7) | ((g ^ m) & 7);
  return m * 1024 + g * 8;
}

// ---------------------------------------------------------------------------
// MFMA GEMM for f32 activations: C[1024][N] = A[1024][1024] @ Wblob^T + bias.
// Grid = (N/256 slices)*64 groups, bid = cs*64+g. 16 waves; wave wv stages
// token-row wv (f32->bf16->swz LDS) then computes col-tile ct=cs*16+wv.
// EPI: 0 plain, 1 gelu(exact), 2 +resid.
// ---------------------------------------------------------------------------
template <int EPI>
__global__ __launch_bounds__(1024) void k_mg(
    const float* __restrict__ A, const u16* __restrict__ blob,
    const float* __restrict__ bias, float* __restrict__ C, int N,
    const float* __restrict__ resid) {
  __shared__ __align__(16) u16 bufA[16 * 1024];
  int tid = threadIdx.x;
  int bid = blockIdx.x;
  int cs = bid >> 6, g = bid & 63;
  int wv = tid >> 6, lane = tid & 63;
  int row16 = lane & 15, quad = lane >> 4;
  // ---- stage A rows: wave wv loads token g*16+wv, lane cols [lane*16,+16) ----
  {
    const float* ar = A + (size_t)(g * 16 + wv) * 1024 + lane * 16;
#pragma unroll
    for (int q = 0; q < 4; q++) {
      float4 v = *(const float4*)(ar + q * 4);
      int c = lane * 16 + q * 4;
      bufA[swz(wv, c + 0)] = f2b(v.x); bufA[swz(wv, c + 1)] = f2b(v.y);
      bufA[swz(wv, c + 2)] = f2b(v.z); bufA[swz(wv, c + 3)] = f2b(v.w);
    }
  }
  __syncthreads();
  int ct = cs * 16 + wv;
  int n = cs * 256 + wv * 16 + row16;
  const u16* wb = blob + ((size_t)ct * 2048 + lane) * 8;
  f32x4 acc = {0.f, 0.f, 0.f, 0.f};
#pragma unroll
  for (int kk = 0; kk < 32; kk++) {
    bf16x8 wf = *(const bf16x8*)(wb + kk * 512);
    bf16x8 aF = *(const bf16x8*)(bufA + swz8(row16, kk * 32 + quad * 8));
    acc = __builtin_amdgcn_mfma_f32_16x16x32_bf16(aF, wf, acc, 0, 0, 0);
  }
  float bv = bias[n];
#pragma unroll
  for (int r = 0; r < 4; r++) {
    int tok = g * 16 + quad * 4 + r;
    float v = acc[r] + bv;
    if (EPI == 1) v = 0.5f * v * (1.f + erff(v * 0.70710678118f));
    if (EPI == 2) v += resid[(size_t)tok * 1024 + n];
    C[(size_t)tok * N + n] = v;
  }
}

// ---------------------------------------------------------------------------
// ODE v13 kernels (verified R10: 14.05->3.13ms): fence-free kernel-per-phase.
// ---------------------------------------------------------------------------
// GEMM phase kernel. Grid 256 = 64 token-groups x 4 col-slices, 16 waves.
// PASS 1: h_img[swz] = bf16(relu(src@w1^T + b1))
// PASS 2: zraw[token][col] = f32(src@w2^T)   (bias/resid applied in k_rk4)
template <int PASS>
__global__ __launch_bounds__(1024) void k_og(
    const u16* __restrict__ wp, const float* __restrict__ bias,
    const u16* __restrict__ src_img, u16* __restrict__ h_img,
    float* __restrict__ zraw) {
  __shared__ __align__(16) u16 bufA[16 * 1024];
  int tid = threadIdx.x;
  int bid = blockIdx.x;
  int g = bid >> 2, cg = bid & 3;
  int wvid = tid >> 6, lane = tid & 63;
  int row16 = lane & 15, quad = lane >> 4;
  int n = cg * 256 + wvid * 16 + row16;  // this lane's output column
  int ct = cg * 16 + wvid;               // global col-tile 0..63
  const u16* wb = wp + ((size_t)ct * 2048 + lane) * 8;  // packed frag base
  // ---- stage activation image (32KB) -> LDS (per-lane src, linear dst) ----
  {
    const u16* src = src_img + (size_t)g * 16384 + wvid * 1024 + lane * 8;
    u16* dst = bufA + wvid * 1024;
    __builtin_amdgcn_global_load_lds(
        (const __attribute__((address_space(1))) uint32_t*)src,
        (__attribute__((address_space(3))) uint32_t*)dst, 16, 0, 0);
    __builtin_amdgcn_global_load_lds(
        (const __attribute__((address_space(1))) uint32_t*)(src + 512),
        (__attribute__((address_space(3))) uint32_t*)(dst + 512), 16, 0, 0);
  }
  VMCNT(0);
  __syncthreads();
  // ---- MFMA K-loop (v9-verified fragment path) ----
  f32x4 acc = {0.f, 0.f, 0.f, 0.f};
#pragma unroll
  for (int kk = 0; kk < 32; kk++) {
    bf16x8 wf = *(const bf16x8*)(wb + kk * 512);
    bf16x8 aF = *(const bf16x8*)(bufA + swz8(row16, kk * 32 + quad * 8));
    acc = __builtin_amdgcn_mfma_f32_16x16x32_bf16(aF, wf, acc, 0, 0, 0);
  }
  if (PASS == 1) {
    float bv = bias[n];
#pragma unroll
    for (int r = 0; r < 4; r++) {
      int ml = quad * 4 + r;
      h_img[(size_t)g * 16384 + swz(ml, n)] = f2b(fmaxf(acc[r] + bv, 0.f));
    }
  } else {
#pragma unroll
    for (int r = 0; r < 4; r++) {
      int tok = g * 16 + quad * 4 + r;
      zraw[(size_t)tok * 1024 + n] = acc[r];
    }
  }
}

// Init: y = nvf = xs; act image = bf16(xs); out = xs. Grid 1024 (token/block).
__global__ __launch_bounds__(256) void k_odeinit(
    const float* __restrict__ xs, float* __restrict__ y,
    float* __restrict__ nvf, u16* __restrict__ act_img,
    float* __restrict__ out) {
  int t = blockIdx.x, tid = threadIdx.x;
  int c = tid * 4;
  int g = t >> 4, ml = t & 15;
  float4 v = *(const float4*)(xs + (size_t)t * 1024 + c);
  *(float4*)(y + (size_t)t * 1024 + c) = v;
  *(float4*)(nvf + (size_t)t * 1024 + c) = v;
  *(float4*)(out + (size_t)t * 1024 + c) = v;
  u16* ag = act_img + (size_t)g * 16384;
  ag[swz(ml, c + 0)] = f2b(v.x); ag[swz(ml, c + 1)] = f2b(v.y);
  ag[swz(ml, c + 2)] = f2b(v.z); ag[swz(ml, c + 3)] = f2b(v.w);
}

// RK4 + LN epilogue. Grid 1024 (token/block), 256 thr.
__global__ __launch_bounds__(256) void k_rk4(
    const float* __restrict__ zraw, const float* __restrict__ b2,
    const float* __restrict__ ng, const float* __restrict__ nb,
    float* __restrict__ y, float* __restrict__ accr,
    float* __restrict__ nvf, u16* __restrict__ act_img,
    float* __restrict__ out, const float* __restrict__ lead,
    int s, int ph) {
  __shared__ float red[8];
  int t = blockIdx.x, tid = threadIdx.x;
  int c = tid * 4;
  int g = t >> 4, ml = t & 15;
  float4 zr = *(const float4*)(zraw + (size_t)t * 1024 + c);
  float4 bb = *(const float4*)(b2 + c);
  float4 nv = *(const float4*)(nvf + (size_t)t * 1024 + c);
  float z0 = zr.x + bb.x + nv.x, z1 = zr.y + bb.y + nv.y;
  float z2 = zr.z + bb.z + nv.z, z3 = zr.w + bb.w + nv.w;
  float s1 = z0 + z1 + z2 + z3;
  float s2 = z0 * z0 + z1 * z1 + z2 * z2 + z3 * z3;
  for (int off = 1; off < 64; off <<= 1) {
    s1 += __shfl_xor(s1, off); s2 += __shfl_xor(s2, off);
  }
  if ((tid & 63) == 0) { red[(tid >> 6) * 2] = s1; red[(tid >> 6) * 2 + 1] = s2; }
  __syncthreads();
  s1 = red[0] + red[2] + red[4] + red[6];
  s2 = red[1] + red[3] + red[5] + red[7];
  float mean = s1 * (1.f / 1024.f);
  float var = s2 * (1.f / 1024.f) - mean * mean;
  float rstd = rsqrtf(var + EPSF);
  float4 gv = *(const float4*)(ng + c);
  float4 bv = *(const float4*)(nb + c);
  float k0 = (z0 - mean) * rstd * gv.x + bv.x;
  float k1 = (z1 - mean) * rstd * gv.y + bv.y;
  float k2 = (z2 - mean) * rstd * gv.z + bv.z;
  float k3 = (z3 - mean) * rstd * gv.w + bv.w;
  float4 yv = *(const float4*)(y + (size_t)t * 1024 + c);
  float4 ac;
  float cf = (ph < 2) ? 0.5f * RESF : RESF;
  const float h6 = RESF / 6.0f;
  float4 nn;
  if (ph == 0) {
    ac.x = k0; ac.y = k1; ac.z = k2; ac.w = k3;
    nn.x = yv.x + cf * k0; nn.y = yv.y + cf * k1;
    nn.z = yv.z + cf * k2; nn.w = yv.w + cf * k3;
    *(float4*)(accr + (size_t)t * 1024 + c) = ac;
  } else if (ph < 3) {
    ac = *(const float4*)(accr + (size_t)t * 1024 + c);
    ac.x += 2.f * k0; ac.y += 2.f * k1; ac.z += 2.f * k2; ac.w += 2.f * k3;
    nn.x = yv.x + cf * k0; nn.y = yv.y + cf * k1;
    nn.z = yv.z + cf * k2; nn.w = yv.w + cf * k3;
    *(float4*)(accr + (size_t)t * 1024 + c) = ac;
  } else {
    ac = *(const float4*)(accr + (size_t)t * 1024 + c);
    yv.x += h6 * (ac.x + k0); yv.y += h6 * (ac.y + k1);
    yv.z += h6 * (ac.z + k2); yv.w += h6 * (ac.w + k3);
    nn = yv;
    *(float4*)(y + (size_t)t * 1024 + c) = yv;
    int idxb = (int)roundf(lead[t >> 9] * 100.0f);
    if ((s + 1) == idxb)
      *(float4*)(out + (size_t)t * 1024 + c) = yv;
  }
  *(float4*)(nvf + (size_t)t * 1024 + c) = nn;
  u16* ag = act_img + (size_t)g * 16384;
  ag[swz(ml, c + 0)] = f2b(nn.x); ag[swz(ml, c + 1)] = f2b(nn.y);
  ag[swz(ml, c + 2)] = f2b(nn.z); ag[swz(ml, c + 3)] = f2b(nn.w);
}

// ---------------------------------------------------------------------------
// Unpatchify: y3[m][p*10+q*5+c] -> out[b][c][hh*2+p][ww*2+q], FLOAT32
// ---------------------------------------------------------------------------
__global__ __launch_bounds__(256) void k_unpatch(
    const float* __restrict__ y3, float* __restrict__ outp) {
  int o = blockIdx.x * 256 + threadIdx.x;
  if (o >= 20480) return;
  int b = o / 10240;
  int c = (o / 2048) % 5;
  int hrow = (o / 64) % 32;
  int wcol = o % 64;
  int hh = hrow >> 1, p = hrow & 1, ww = wcol >> 1, q = wcol & 1;
  int m2 = b * 512 + hh * 32 + ww;
  int colj = p * 10 + q * 5 + c;
  outp[o] = y3[(size_t)m2 * 20 + colj];
}

// ===========================================================================
extern "C" void kernel_launch(void* const* d_in, const int* in_sizes, int n_in,
                              void* d_out, int out_size, void* d_ws, size_t ws_size,
                              hipStream_t stream) {
  const float* x         = (const float*)d_in[0];
  const float* lead      = (const float*)d_in[1];
  const float* patch_w   = (const float*)d_in[2];
  const float* patch_b   = (const float*)d_in[3];
  const float* var_embed = (const float*)d_in[4];
  const float* var_query = (const float*)d_in[5];
  const float* agg_in_w  = (const float*)d_in[6];
  const float* agg_in_b  = (const float*)d_in[7];
  const float* agg_out_w = (const float*)d_in[8];
  const float* agg_out_b = (const float*)d_in[9];
  const float* pos_embed = (const float*)d_in[10];
  const float* lt_w      = (const float*)d_in[11];
  const float* lt_b      = (const float*)d_in[12];
  const float* blk_qkv_w = (const float*)d_in[13];
  const float* blk_qkv_b = (const float*)d_in[14];
  const float* blk_out_w = (const float*)d_in[15];
  const float* blk_out_b = (const float*)d_in[16];
  const float* blk_n1_g  = (const float*)d_in[17];
  const float* blk_n1_b  = (const float*)d_in[18];
  const float* blk_n2_g  = (const float*)d_in[19];
  const float* blk_n2_b  = (const float*)d_in[20];
  const float* ode_w1    = (const float*)d_in[21];
  const float* ode_b1    = (const float*)d_in[22];
  const float* ode_w2    = (const float*)d_in[23];
  const float* ode_b2    = (const float*)d_in[24];
  const float* ode_ng    = (const float*)d_in[25];
  const float* ode_nb    = (const float*)d_in[26];
  const float* norm_g    = (const float*)d_in[27];
  const float* norm_b    = (const float*)d_in[28];
  const float* h1_w      = (const float*)d_in[29];
  const float* h1_b      = (const float*)d_in[30];
  const float* h2_w      = (const float*)d_in[31];
  const float* h2_b      = (const float*)d_in[32];
  const float* hf_w      = (const float*)d_in[33];
  const float* hf_b      = (const float*)d_in[34];
  (void)in_sizes; (void)n_in; (void)out_size; (void)ws_size;

  float* ws = (float*)d_ws;
  // ODE buffers in ode-dead regions (qkv/attno/t1):
  u16*   act16 = (u16*)(ws + 0);        // 2MB act image
  u16*   h16   = (u16*)(ws + 524288);   // 2MB h image
  float* zraw  = ws + 1048576;          // 4MB raw GEMM2 out
  float* ybuf  = ws + 2097152;          // 4MB RK4 y      (end 3145728)
  float* accr  = ws + 3145728;          // 4MB RK4 accum  (attno region)
  float* nvf   = ws + 4194304;          // 4MB f32 act    (t1 region)
  float* patches = ws + 0;         // 20480 (stage-1 only; dead before ode)
  float* qvec    = ws + 20480;     // 1024
  float* qb      = ws + 21504;     // 256 (16 used)
  float* u       = ws + 21760;     // 16384
  float* PU      = ws + 38144;     // 320
  float* C0      = ws + 38464;     // 80 (pad to 40960)
  float* amat    = ws + 40960;     // 81920
  float* PW      = ws + 122880;    // 20480
  float* CV      = ws + 143360;    // 5120  (end 148480)
  float* agg     = ws + 3145728;   // 1048576 (attno slot; dead by then)
  float* qkv   = ws + 0;           // 3145728
  float* attno = ws + 3145728;     // 1048576
  float* t1    = ws + 4194304;     // 1048576
  float* odeo  = ws + 5242880;     // 1048576
  float* xs    = ws + 6291456;     // 1048576
  u16*   w16a  = (u16*)(ws + 7340032);  // packed ode w1 (bf16 frag blob)
  u16*   w16b  = (u16*)(ws + 7864320);  // packed ode w2
  // transient GEMM weight blobs (lifetimes verified against region uses):
  u16*   qkvblob = (u16*)(ws + 3145728); // 6MB in attno+t1 (dead until attn)
  u16*   aoblob  = (u16*)(ws + 5242880); // 2MB in odeo (dead until ODE init)
  u16*   hblob   = (u16*)(ws + 3145728); // 2MB in attno region (head only)
  float* y1 = ws + 0;
  float* y2 = ws + 1048576;
  float* y3 = ws + 2097152;        // 20480

  // ---- stage 1 ----
  k_patches<<<dim3(80), dim3(256), 0, stream>>>(x, patches);
  k_qvec<<<dim3(64), dim3(256), 0, stream>>>(var_query, agg_in_w, agg_in_b, qvec);
  k_qb<<<dim3(1), dim3(256), 0, stream>>>(qvec, agg_in_b + 1024, qb);
  k_u<<<dim3(64), dim3(256), 0, stream>>>(qvec, agg_in_w + (size_t)1024 * 1024, u);
  k_pu<<<dim3(80), dim3(256), 0, stream>>>(patch_w, patch_b, var_embed, u, qb, PU, C0);
  k_pw<<<dim3(5120), dim3(256), 0, stream>>>(
      agg_in_w + (size_t)2048 * 1024, agg_in_b + 2048, patch_w, patch_b,
      var_embed, PW, CV);
  k_scoresm<<<dim3(1024), dim3(256), 0, stream>>>(patches, PU, C0, amat);
  k_agg<<<dim3(1024), dim3(256), 0, stream>>>(patches, PW, CV, amat, agg);
  k_gemm<3><<<dim3(16, 16), dim3(256), 0, stream>>>(
      agg, agg_out_w, agg_out_b, xs, 1024, 1024, 1024,
      nullptr, pos_embed, lt_w, lt_b, lead);

  // ---- transformer blocks ----
  for (int i = 0; i < 2; i++) {
    // qkv = xs @ Wqkv^T + b  (bf16 MFMA; blob in attno+t1, dead until attn)
    k_pack<<<dim3(12288), dim3(256), 0, stream>>>(
        blk_qkv_w + (size_t)i * 3072 * 1024, qkvblob);
    k_mg<0><<<dim3(768), dim3(1024), 0, stream>>>(
        xs, qkvblob, blk_qkv_b + i * 3072, qkv, 3072, nullptr);
    k_attn<<<dim3(1024), dim3(256), 0, stream>>>(qkv, attno);
    // t1 = attno @ Wout^T + b + xs  (bf16 MFMA; blob in odeo region)
    k_pack<<<dim3(4096), dim3(256), 0, stream>>>(
        blk_out_w + (size_t)i * 1048576, aoblob);
    k_mg<2><<<dim3(256), dim3(1024), 0, stream>>>(
        attno, aoblob, blk_out_b + i * 1024, t1, 1024, xs);
    k_ln<<<dim3(1024), dim3(256), 0, stream>>>(
        t1, (const float*)nullptr, blk_n1_g + i * 1024, blk_n1_b + i * 1024, xs);
    k_pack<<<dim3(4096), dim3(256), 0, stream>>>(
        ode_w1 + (size_t)i * 1048576, w16a);
    k_pack<<<dim3(4096), dim3(256), 0, stream>>>(
        ode_w2 + (size_t)i * 1048576, w16b);
    // ---- fence-free ODE: 3 kernels per RK4 phase (v13-verified) ----
    k_odeinit<<<dim3(1024), dim3(256), 0, stream>>>(xs, ybuf, nvf, act16, odeo);
    for (int s = 0; s < NSTEPS; s++) {
      for (int ph = 0; ph < 4; ph++) {
        k_og<1><<<dim3(256), dim3(1024), 0, stream>>>(
            w16a, ode_b1 + i * 1024, act16, h16, nullptr);
        k_og<2><<<dim3(256), dim3(1024), 0, stream>>>(
            w16b, nullptr, h16, nullptr, zraw);
        k_rk4<<<dim3(1024), dim3(256), 0, stream>>>(
            zraw, ode_b2 + i * 1024, ode_ng + i * 1024, ode_nb + i * 1024,
            ybuf, accr, nvf, act16, odeo, lead, s, ph);
      }
    }
    k_ln<<<dim3(1024), dim3(256), 0, stream>>>(
        xs, odeo, blk_n2_g + i * 1024, blk_n2_b + i * 1024, xs);
  }

  // ---- head ----
  k_ln<<<dim3(1024), dim3(256), 0, stream>>>(
      xs, (const float*)nullptr, norm_g, norm_b, xs);
  k_pack<<<dim3(4096), dim3(256), 0, stream>>>(h1_w, hblob);
  k_mg<1><<<dim3(256), dim3(1024), 0, stream>>>(
      xs, hblob, h1_b, y1, 1024, nullptr);
  k_pack<<<dim3(4096), dim3(256), 0, stream>>>(h2_w, hblob);
  k_mg<1><<<dim3(256), dim3(1024), 0, stream>>>(
      y1, hblob, h2_b, y2, 1024, nullptr);
  k_gemm<0><<<dim3(1, 16), dim3(256), 0, stream>>>(
      y2, hf_w, hf_b, y3, 1024, 20, 1024, nullptr, nullptr, nullptr, nullptr, nullptr);
  k_unpatch<<<dim3(80), dim3(256), 0, stream>>>(y3, (float*)d_out);
}